// Round 3
// baseline (1033.086 us; speedup 1.0000x reference)
//
#include <hip/hip_runtime.h>
#include <stdint.h>

#define NR 32768
#define MM 8
#define NCLS 100
#define HALFN 1048576u
#define HSS 264   // ushort stride for h planes (16B-aligned rows, conflict-free b128 frags)
#define LGS 260   // float stride for logit rows

typedef __bf16 bf8 __attribute__((ext_vector_type(8)));
typedef float f4 __attribute__((ext_vector_type(4)));
typedef unsigned long long ull;

// ---------------- threefry2x32 (exact JAX semantics) ----------------
__host__ __device__ inline void tf2x32(uint32_t k0, uint32_t k1, uint32_t x0, uint32_t x1,
                                       uint32_t& o0, uint32_t& o1) {
  uint32_t ks0 = k0, ks1 = k1, ks2 = k0 ^ k1 ^ 0x1BD11BDAu;
  x0 += ks0; x1 += ks1;
#define TFR(r) { x0 += x1; x1 = (x1 << r) | (x1 >> (32 - r)); x1 ^= x0; }
  TFR(13) TFR(15) TFR(26) TFR(6)  x0 += ks1; x1 += ks2 + 1u;
  TFR(17) TFR(29) TFR(16) TFR(24) x0 += ks2; x1 += ks0 + 2u;
  TFR(13) TFR(15) TFR(26) TFR(6)  x0 += ks0; x1 += ks1 + 3u;
  TFR(17) TFR(29) TFR(16) TFR(24) x0 += ks1; x1 += ks2 + 4u;
  TFR(13) TFR(15) TFR(26) TFR(6)  x0 += ks2; x1 += ks0 + 5u;
#undef TFR
  o0 = x0; o1 = x1;
}

__device__ inline float tf_uniform(uint32_t k0, uint32_t k1, uint32_t i) {
  uint32_t o0, o1, b;
  if (i < HALFN) { tf2x32(k0, k1, i, i + HALFN, o0, o1); b = o0; }
  else           { tf2x32(k0, k1, i - HALFN, i, o0, o1); b = o1; }
  return __uint_as_float((b >> 9) | 0x3F800000u) - 1.0f;
}

// template dtype auto-detect: float32 {0,1.0f} / int32 {0,1} / bytes. 4 ones expected.
__device__ inline int load_tmpl(const void* p, int lane) {
  const unsigned* pi = (const unsigned*)p;
  unsigned w = pi[lane];
  ull okF = __ballot(w == 0u || w == 0x3F800000u);
  ull onF = __ballot(w == 0x3F800000u);
  ull okI = __ballot(w <= 1u);
  ull onI = __ballot(w == 1u);
  if (okF == ~0ull && __popcll(onF) == 4) return (w == 0x3F800000u) ? 1 : 0;
  if (okI == ~0ull && __popcll(onI) == 4) return (int)w;
  const unsigned char* pb = (const unsigned char*)p;
  return pb[lane] ? 1 : 0;
}

__device__ inline float rdlane(float v, int l) {
  return __int_as_float(__builtin_amdgcn_readlane(__float_as_int(v), l));
}

// ---------------- pack W2 into MFMA B-fragment order, bf16 hi + lo ----------
__global__ __launch_bounds__(256) void packW2(const float* __restrict__ W2, ushort* __restrict__ Wp) {
  int idx = blockIdx.x * 256 + threadIdx.x;   // source index: m*65536 + k*256 + c
  int c = idx & 255, k = (idx >> 8) & 255, m = idx >> 16;
  float v = W2[idx];
  int kt = k >> 5, q = (k >> 3) & 3, j = k & 7;
  int NT = c >> 4, lr = c & 15;
  int didx = ((((m * 8 + kt) * 16 + NT) * 64) + q * 16 + lr) * 8 + j;
  union { __bf16 b; ushort u; } cv;
  __bf16 hi = (__bf16)v;
  cv.b = hi; Wp[didx] = cv.u;
  cv.b = (__bf16)(v - (float)hi); Wp[(1 << 19) + didx] = cv.u;
}

// ---------------- pack W1 into layer-1 B-frags with 3-term K-packing --------
// B[k=q*8+j][n]: q0 -> W1hi, q1 -> W1lo, q2 -> W1hi, q3 -> 0
__global__ __launch_bounds__(256) void packW1(const float* __restrict__ W1, ushort* __restrict__ Wp1) {
  int idx = blockIdx.x * 256 + threadIdx.x;  // (m, nt, lane): 8*16*64 = 8192
  int lane = idx & 63, nt = (idx >> 6) & 15, m = idx >> 10;
  int q = lane >> 4, lr = lane & 15;
#pragma unroll
  for (int j = 0; j < 8; j++) {
    float v = (q == 3) ? 0.0f : W1[(size_t)(m * 8 + j) * 256 + nt * 16 + lr];
    __bf16 hi = (__bf16)v;
    __bf16 outb = (q == 1) ? (__bf16)(v - (float)hi) : hi;
    union { __bf16 b; ushort u; } cv; cv.b = outb;
    Wp1[(size_t)idx * 8 + j] = cv.u;
  }
}

// ---------------- stage2: centroid bits ----------------
__global__ void stage2(const float* __restrict__ centroids, const int* __restrict__ perm,
                       ull* __restrict__ cb64) {
  int c = threadIdx.x;
  if (c >= 128) return;
  ull bits = 0;
  if (c < NCLS)
    for (int j = 0; j < 64; j++)
      if (centroids[c * 64 + perm[j]] > 0.0f) bits |= (1ull << j);
  cb64[c] = bits;
}

// ---------------- stage1: permute, flips, targets, y scan, hamming -----------
__global__ __launch_bounds__(256) void stage1(
    const float* __restrict__ x, const int* __restrict__ y, const int* __restrict__ perm,
    const void* tmap, const void* traw,
    uint32_t km0, uint32_t km1, uint32_t kr0, uint32_t kr1,
    float* __restrict__ xp, float* __restrict__ xm,
    ull* __restrict__ targ, const ull* __restrict__ cb64,
    float* __restrict__ winv, unsigned char* __restrict__ poslist, int* __restrict__ nposA,
    float* __restrict__ acc) {
  int wv = threadIdx.x >> 6, lane = threadIdx.x & 63;
  int n = blockIdx.x * 4 + wv;
  __shared__ float shh[2];
  if (threadIdx.x == 0) { shh[0] = 0.0f; shh[1] = 0.0f; }
  __syncthreads();

  int tm = load_tmpl(tmap, lane);
  int tr = load_tmpl(traw, lane);
  float xpv = x[n * 64 + perm[lane]];
  uint32_t i = (uint32_t)(n * 64 + lane);

  float um = tf_uniform(km0, km1, i);
  int rank = 0;
#pragma unroll 16
  for (int k = 0; k < 64; k++) {
    float vk = rdlane(um, k);
    rank += (vk < um) || (vk == um && k < lane);
  }
  ull fm = tm ? (1ull << rank) : 0ull;
#pragma unroll
  for (int off = 1; off < 64; off <<= 1) fm |= __shfl_xor(fm, off);

  float ur = tf_uniform(kr0, kr1, i);
  rank = 0;
#pragma unroll 16
  for (int k = 0; k < 64; k++) {
    float vk = rdlane(ur, k);
    rank += (vk < ur) || (vk == ur && k < lane);
  }
  ull fr = tr ? (1ull << rank) : 0ull;
#pragma unroll
  for (int off = 1; off < 64; off <<= 1) fr |= __shfl_xor(fr, off);

  float xmv = ((fm >> lane) & 1ull) ? -xpv : xpv;
  float rfv = ((fr >> lane) & 1ull) ? -xpv : xpv;
  xp[n * 64 + lane] = xpv;
  xm[n * 64 + lane] = xmv;
  ull t64 = __ballot(rfv > 0.0f);
  ull b64v = __ballot(xpv > 0.0f);

  int c1 = y[(size_t)n * NCLS + lane] > 0;
  int c2 = (lane < NCLS - 64) ? (y[(size_t)n * NCLS + 64 + lane] > 0) : 0;
  ull p0 = __ballot(c1);
  ull p1 = __ballot(c2);
  int cnt0 = __popcll(p0);
  float cnt = (float)(cnt0 + __popcll(p1));

  // parallel poslist scatter (ascending class order preserved)
  unsigned char* pl = poslist + (size_t)n * 64;
  ull below = (lane == 0) ? 0ull : (~0ull >> (64 - lane));
  if (c1) pl[__popcll(p0 & below)] = (unsigned char)lane;
  if (c2) pl[cnt0 + __popcll(p1 & below)] = (unsigned char)(64 + lane);

  // hamming contribution
  float px = (float)__popcll(b64v);
  float hsum = 0.0f;
  if (c1) { ull cb = cb64[lane]; hsum += px + (float)__popcll(cb) - 2.0f * (float)__popcll(b64v & cb); }
  if (c2) { ull cb = cb64[64 + lane]; hsum += px + (float)__popcll(cb) - 2.0f * (float)__popcll(b64v & cb); }
#pragma unroll
  for (int off = 1; off < 64; off <<= 1) hsum += __shfl_xor(hsum, off);

  if (lane == 0) {
    targ[n] = t64;
    winv[n] = 1.0f / cnt;
    nposA[n] = cnt0 + __popcll(p1);
    atomicAdd(&shh[0], hsum);
    atomicAdd(&shh[1], cnt);
  }
  __syncthreads();
  if (threadIdx.x == 0) { atomicAdd(&acc[3], shh[0]); atomicAdd(&acc[4], shh[1]); }
}

// ---------------- fused MLP (all-MFMA) + loss epilogue ----------------
// grid (512, 8, 2); block 256. pass0 = map (split-precision), pass1 = net.
__global__ __launch_bounds__(256, 2) void mapnet3(
    const float* __restrict__ Xm, const float* __restrict__ Xp,
    const ushort* __restrict__ Wp1, const float* __restrict__ B1,
    const ushort* __restrict__ Wp, const float* __restrict__ B2,
    const ull* __restrict__ targ, const float* __restrict__ winv,
    const unsigned char* __restrict__ poslist, const int* __restrict__ nposA,
    const ull* __restrict__ cb64, float* __restrict__ accg) {
  __shared__ union {
    ushort h[2 * 64 * HSS];    // hi plane [0..), lo plane [64*HSS..)
    float lg[32 * LGS];        // logit staging, aliases hi plane after K-loop
  } u;
  const int tid = threadIdx.x, lane = tid & 63, wv = tid >> 6;
  const int q = lane >> 4, lr = lane & 15;
  const int m = blockIdx.y, pass = blockIdx.z;
  const int n0 = blockIdx.x * 64;
  const float* Xin = pass ? Xp : Xm;

  // ---- layer 1 via MFMA: A = x packed (q0:xh, q1:xh, q2:xl, q3:0) ----
  bf8 af[4];
#pragma unroll
  for (int rt = 0; rt < 4; rt++) {
    const float* xsrc = Xin + (size_t)(n0 + rt * 16 + lr) * 64 + m * 8;
    f4 v0 = *(const f4*)xsrc;
    f4 v1 = *(const f4*)(xsrc + 4);
    float vf[8] = {v0.x, v0.y, v0.z, v0.w, v1.x, v1.y, v1.z, v1.w};
    bf8 a;
#pragma unroll
    for (int j = 0; j < 8; j++) {
      float f = vf[j];
      __bf16 hi = (__bf16)f;
      __bf16 el = (q == 2) ? (__bf16)(f - (float)hi) : hi;
      a[j] = (q == 3) ? (__bf16)0.0f : el;
    }
    af[rt] = a;
  }
  {
    f4 z[4][4];
#pragma unroll
    for (int nt = 0; nt < 4; nt++) {
      bf8 bf = *(const bf8*)(Wp1 + ((size_t)(m * 16 + wv * 4 + nt) * 64 + lane) * 8);
#pragma unroll
      for (int rt = 0; rt < 4; rt++)
        z[rt][nt] = __builtin_amdgcn_mfma_f32_16x16x32_bf16(af[rt], bf, (f4){0.f, 0.f, 0.f, 0.f}, 0, 0, 0);
    }
#pragma unroll
    for (int nt = 0; nt < 4; nt++) {
      float bv1 = B1[m * 256 + wv * 64 + nt * 16 + lr];
      int col = wv * 64 + nt * 16 + lr;
#pragma unroll
      for (int rt = 0; rt < 4; rt++)
#pragma unroll
        for (int reg = 0; reg < 4; reg++) {
          float zz = z[rt][nt][reg] + bv1;
          float h = zz / (1.0f + __expf(-zz));
          int row = rt * 16 + q * 4 + reg;
          union { __bf16 b; ushort us; } cv;
          __bf16 hi = (__bf16)h;
          cv.b = hi;
          u.h[row * HSS + col] = cv.us;
          if (pass == 0) {
            cv.b = (__bf16)(h - (float)hi);
            u.h[64 * HSS + row * HSS + col] = cv.us;
          }
        }
    }
  }
  __syncthreads();

  // ---- K loop: wave wv owns cols wv*64..+63 ----
  f4 acc4[4][4];
#pragma unroll
  for (int rt = 0; rt < 4; rt++)
#pragma unroll
    for (int nt = 0; nt < 4; nt++) acc4[rt][nt] = (f4){0.f, 0.f, 0.f, 0.f};

  const size_t wbase = (size_t)m * 8 * 16 * 64 * 8;
#pragma unroll 2
  for (int kt = 0; kt < 8; kt++) {
    bf8 ah[4], al[4];
#pragma unroll
    for (int rt = 0; rt < 4; rt++) {
      int off = (rt * 16 + lr) * HSS + kt * 32 + q * 8;
      ah[rt] = *(const bf8*)(u.h + off);
      if (pass == 0) al[rt] = *(const bf8*)(u.h + 64 * HSS + off);
    }
#pragma unroll
    for (int nt = 0; nt < 4; nt++) {
      const ushort* bp = Wp + wbase + (((size_t)kt * 16 + (wv * 4 + nt)) * 64 + lane) * 8;
      bf8 bh = *(const bf8*)bp;
      if (pass == 0) {
        bf8 bl = *(const bf8*)(bp + (1 << 19));
#pragma unroll
        for (int rt = 0; rt < 4; rt++) {
          acc4[rt][nt] = __builtin_amdgcn_mfma_f32_16x16x32_bf16(ah[rt], bh, acc4[rt][nt], 0, 0, 0);
          acc4[rt][nt] = __builtin_amdgcn_mfma_f32_16x16x32_bf16(al[rt], bh, acc4[rt][nt], 0, 0, 0);
          acc4[rt][nt] = __builtin_amdgcn_mfma_f32_16x16x32_bf16(ah[rt], bl, acc4[rt][nt], 0, 0, 0);
        }
      } else {
#pragma unroll
        for (int rt = 0; rt < 4; rt++)
          acc4[rt][nt] = __builtin_amdgcn_mfma_f32_16x16x32_bf16(ah[rt], bh, acc4[rt][nt], 0, 0, 0);
      }
    }
  }

  float bv[4];
#pragma unroll
  for (int nt = 0; nt < 4; nt++) bv[nt] = B2[m * 256 + wv * 64 + nt * 16 + lr];

  // ---- epilogue: two 32-row phases through LDS, vectorized reads ----
  float partLoss = 0.0f, partHit = 0.0f;
  for (int ph = 0; ph < 2; ph++) {
    __syncthreads();
#pragma unroll
    for (int rt2 = 0; rt2 < 2; rt2++) {
      int rt = ph * 2 + rt2;
#pragma unroll
      for (int nt = 0; nt < 4; nt++)
#pragma unroll
        for (int reg = 0; reg < 4; reg++) {
          int row = rt2 * 16 + q * 4 + reg;
          u.lg[row * LGS + wv * 64 + nt * 16 + lr] = acc4[rt][nt][reg] + bv[nt];
        }
    }
    __syncthreads();
    int rl = wv * 8 + (lane >> 3);       // local row 0..31
    int n = n0 + ph * 32 + rl;
    int cj = lane & 7;                   // 8 lanes per row; lane cj owns cols cj*4 + 32k + e
    const float* lrow = u.lg + rl * LGS;
    f4 vv[8];
#pragma unroll
    for (int k = 0; k < 8; k++) vv[k] = *(const f4*)(lrow + cj * 4 + k * 32);
    if (pass == 0) {
      float mv = -1e30f; int mi = 0;
#pragma unroll
      for (int k = 0; k < 8; k++)
#pragma unroll
        for (int e = 0; e < 4; e++) {
          float v = vv[k][e];
          int c = cj * 4 + k * 32 + e;
          if (v > mv) { mv = v; mi = c; }
        }
#pragma unroll
      for (int off = 1; off < 8; off <<= 1) {
        float om = __shfl_xor(mv, off); int oi = __shfl_xor(mi, off);
        if (om > mv || (om == mv && oi < mi)) { mv = om; mi = oi; }
      }
      float s = 0.0f;
#pragma unroll
      for (int k = 0; k < 8; k++)
#pragma unroll
        for (int e = 0; e < 4; e++) s += __expf(vv[k][e] - mv);
#pragma unroll
      for (int off = 1; off < 8; off <<= 1) s += __shfl_xor(s, off);
      if (cj == 0) {
        float lse = mv + __logf(s);
        int t = (int)((targ[n] >> (m * 8)) & 0xFFull);
        partLoss += lse - lrow[t];
        partHit += (mi == t) ? 1.0f : 0.0f;
      }
    } else {
      float s = 0.0f;
#pragma unroll
      for (int k = 0; k < 8; k++)
#pragma unroll
        for (int e = 0; e < 4; e++) s += __expf(vv[k][e]);
#pragma unroll
      for (int off = 1; off < 8; off <<= 1) s += __shfl_xor(s, off);
      int np = nposA[n];
      const unsigned char* pl = poslist + (size_t)n * 64;
      float sp = 0.0f;
      for (int j2 = cj; j2 < np; j2 += 8) {
        int c = pl[j2];
        int t = (int)((cb64[c] >> (m * 8)) & 0xFFull);
        sp += lrow[t];
      }
#pragma unroll
      for (int off = 1; off < 8; off <<= 1) sp += __shfl_xor(sp, off);
      if (cj == 0) partLoss += __logf(s) - winv[n] * sp;
    }
  }
#pragma unroll
  for (int off = 1; off < 64; off <<= 1) {
    partLoss += __shfl_xor(partLoss, off);
    partHit += __shfl_xor(partHit, off);
  }
  if (lane == 0) {
    if (pass == 0) { atomicAdd(&accg[0], partLoss); atomicAdd(&accg[2], partHit); }
    else           { atomicAdd(&accg[1], partLoss); }
  }
}

__global__ void finalk(const float* __restrict__ acc, float* __restrict__ out) {
  float netLoss = acc[1] / (float)NR;
  float mapLoss = acc[0] / (float)NR;
  out[0] = netLoss + mapLoss;
  out[1] = netLoss;
  out[2] = mapLoss;
  out[3] = acc[2] / (float)(NR * MM);
  out[4] = acc[3] / acc[4];
}

extern "C" void kernel_launch(void* const* d_in, const int* in_sizes, int n_in,
                              void* d_out, int out_size, void* d_ws, size_t ws_size,
                              hipStream_t stream) {
  const float* x = (const float*)d_in[0];
  const int* y = (const int*)d_in[1];
  const float* centroids = (const float*)d_in[2];
  const int* perm = (const int*)d_in[3];
  const void* tmap = d_in[4];
  const void* traw = d_in[5];
  const float* W1 = (const float*)d_in[6];
  const float* B1 = (const float*)d_in[7];
  const float* W2 = (const float*)d_in[8];
  const float* B2 = (const float*)d_in[9];
  float* out = (float*)d_out;

  char* w = (char*)d_ws;
  float* acc = (float*)w;                                     // 256 B reserved
  float* xp = (float*)(w + 256);                              // 8 MB
  float* xm = xp + (size_t)NR * 64;                           // 8 MB
  ull* targ = (ull*)(xm + (size_t)NR * 64);                   // 256 KB
  ull* cb64 = targ + NR;                                      // 1 KB (128 slots)
  float* winv = (float*)(cb64 + 128);                         // 128 KB
  int* nposA = (int*)(winv + NR);                             // 128 KB
  unsigned char* poslist = (unsigned char*)(nposA + NR);      // 2 MB
  ushort* Wp = (ushort*)(poslist + (size_t)NR * 64);          // 2 MB (hi + lo)
  ushort* Wp1 = Wp + (1 << 20);                               // 128 KB (layer-1 frags)

  hipMemsetAsync(acc, 0, 64, stream);

  // jax.random.key(1) -> (0,1); split -> kmap=(w0(0,2), w0(1,3)), kraw=(w1(0,2), w1(1,3))
  uint32_t a0, b0, a1, b1;
  tf2x32(0u, 1u, 0u, 2u, a0, b0);
  tf2x32(0u, 1u, 1u, 3u, a1, b1);

  packW2<<<2048, 256, 0, stream>>>(W2, Wp);
  packW1<<<32, 256, 0, stream>>>(W1, Wp1);
  stage2<<<1, 128, 0, stream>>>(centroids, perm, cb64);
  stage1<<<NR / 4, 256, 0, stream>>>(x, y, perm, tmap, traw, a0, a1, b0, b1,
                                     xp, xm, targ, cb64, winv, poslist, nposA, acc);
  dim3 g(NR / 64, MM, 2);
  mapnet3<<<g, 256, 0, stream>>>(xm, xp, Wp1, B1, Wp, B2, targ, winv, poslist, nposA, cb64, acc);
  finalk<<<1, 1, 0, stream>>>(acc, out);
}

// Round 4
// 1020.000 us; speedup vs baseline: 1.0128x; 1.0128x over previous
//
#include <hip/hip_runtime.h>
#include <stdint.h>

#define NR 32768
#define MM 8
#define NCLS 100
#define HALFN 1048576u
#define HSS 264   // ushort stride for h plane rows (16B-aligned, conflict-minimal)
#define LGS 260   // float stride for logit rows

typedef __bf16 bf8 __attribute__((ext_vector_type(8)));
typedef float f4 __attribute__((ext_vector_type(4)));
typedef ushort us4 __attribute__((ext_vector_type(4)));
typedef unsigned long long ull;

// ---------------- threefry2x32 (exact JAX semantics) ----------------
__host__ __device__ inline void tf2x32(uint32_t k0, uint32_t k1, uint32_t x0, uint32_t x1,
                                       uint32_t& o0, uint32_t& o1) {
  uint32_t ks0 = k0, ks1 = k1, ks2 = k0 ^ k1 ^ 0x1BD11BDAu;
  x0 += ks0; x1 += ks1;
#define TFR(r) { x0 += x1; x1 = (x1 << r) | (x1 >> (32 - r)); x1 ^= x0; }
  TFR(13) TFR(15) TFR(26) TFR(6)  x0 += ks1; x1 += ks2 + 1u;
  TFR(17) TFR(29) TFR(16) TFR(24) x0 += ks2; x1 += ks0 + 2u;
  TFR(13) TFR(15) TFR(26) TFR(6)  x0 += ks0; x1 += ks1 + 3u;
  TFR(17) TFR(29) TFR(16) TFR(24) x0 += ks1; x1 += ks2 + 4u;
  TFR(13) TFR(15) TFR(26) TFR(6)  x0 += ks2; x1 += ks0 + 5u;
#undef TFR
  o0 = x0; o1 = x1;
}

__device__ inline float tf_uniform(uint32_t k0, uint32_t k1, uint32_t i) {
  uint32_t o0, o1, b;
  if (i < HALFN) { tf2x32(k0, k1, i, i + HALFN, o0, o1); b = o0; }
  else           { tf2x32(k0, k1, i - HALFN, i, o0, o1); b = o1; }
  return __uint_as_float((b >> 9) | 0x3F800000u) - 1.0f;
}

// template dtype auto-detect: float32 {0,1.0f} / int32 {0,1} / bytes. 4 ones expected.
__device__ inline int load_tmpl(const void* p, int lane) {
  const unsigned* pi = (const unsigned*)p;
  unsigned w = pi[lane];
  ull okF = __ballot(w == 0u || w == 0x3F800000u);
  ull onF = __ballot(w == 0x3F800000u);
  ull okI = __ballot(w <= 1u);
  ull onI = __ballot(w == 1u);
  if (okF == ~0ull && __popcll(onF) == 4) return (w == 0x3F800000u) ? 1 : 0;
  if (okI == ~0ull && __popcll(onI) == 4) return (int)w;
  const unsigned char* pb = (const unsigned char*)p;
  return pb[lane] ? 1 : 0;
}

__device__ inline float rdlane(float v, int l) {
  return __int_as_float(__builtin_amdgcn_readlane(__float_as_int(v), l));
}

__device__ inline ushort bf16bits(float f) {
  union { __bf16 b; ushort u; } cv; cv.b = (__bf16)f; return cv.u;
}
__device__ inline float bf16val(float f) {
  return (float)(__bf16)f;
}

// ---------------- pack W2 into MFMA B-fragment order, bf16 hi + lo ----------
// Coalesced: thread gid owns frag-slot gid -> 8 contiguous ushorts at Wp[gid*8].
// gid = ((m*8+kt)*16+NT)*64 + q*16+lr ; element j = W2[m][kt*32+q*8+j][NT*16+lr]
__global__ __launch_bounds__(256) void packW2(const float* __restrict__ W2, ushort* __restrict__ Wp) {
  int gid = blockIdx.x * 256 + threadIdx.x;          // 65536 total
  int lane6 = gid & 63, frag = gid >> 6;
  int NT = frag & 15, kt = (frag >> 4) & 7, m = frag >> 7;
  int q = lane6 >> 4, lr = lane6 & 15;
  const float* src = W2 + (size_t)m * 65536 + (size_t)(kt * 32 + q * 8) * 256 + NT * 16 + lr;
  ushort hi[8], lo[8];
#pragma unroll
  for (int j = 0; j < 8; j++) {
    float v = src[j * 256];
    float h = bf16val(v);
    hi[j] = bf16bits(v);
    lo[j] = bf16bits(v - h);
  }
  us4 h0 = {hi[0], hi[1], hi[2], hi[3]}, h1 = {hi[4], hi[5], hi[6], hi[7]};
  us4 l0 = {lo[0], lo[1], lo[2], lo[3]}, l1 = {lo[4], lo[5], lo[6], lo[7]};
  *(us4*)(Wp + (size_t)gid * 8) = h0;
  *(us4*)(Wp + (size_t)gid * 8 + 4) = h1;
  *(us4*)(Wp + (1 << 19) + (size_t)gid * 8) = l0;
  *(us4*)(Wp + (1 << 19) + (size_t)gid * 8 + 4) = l1;
}

// ---------------- pack W1 frags (serves as A-operand of transposed L1) ------
// frag (m, t): lane(q,lr) j -> A[hid=t*16+lr][k=q*8+j]: q0 W1hi, q1 W1lo, q2 W1hi, q3 0
__global__ __launch_bounds__(256) void packW1(const float* __restrict__ W1, ushort* __restrict__ Wp1) {
  int idx = blockIdx.x * 256 + threadIdx.x;  // (m, t, lane): 8*16*64 = 8192
  int lane = idx & 63, t = (idx >> 6) & 15, m = idx >> 10;
  int q = lane >> 4, lr = lane & 15;
#pragma unroll
  for (int j = 0; j < 8; j++) {
    float v = (q == 3) ? 0.0f : W1[(size_t)(m * 8 + j) * 256 + t * 16 + lr];
    float h = bf16val(v);
    Wp1[(size_t)idx * 8 + j] = (q == 1) ? bf16bits(v - h) : bf16bits(v);
  }
}

// ---------------- stage2: centroid bits ----------------
__global__ void stage2(const float* __restrict__ centroids, const int* __restrict__ perm,
                       ull* __restrict__ cb64) {
  int c = threadIdx.x;
  if (c >= 128) return;
  ull bits = 0;
  if (c < NCLS)
    for (int j = 0; j < 64; j++)
      if (centroids[c * 64 + perm[j]] > 0.0f) bits |= (1ull << j);
  cb64[c] = bits;
}

// ---------------- stage1: permute, flips, targets, y scan, hamming -----------
__global__ __launch_bounds__(256) void stage1(
    const float* __restrict__ x, const int* __restrict__ y, const int* __restrict__ perm,
    const void* tmap, const void* traw,
    uint32_t km0, uint32_t km1, uint32_t kr0, uint32_t kr1,
    float* __restrict__ xp, float* __restrict__ xm,
    ull* __restrict__ targ, const ull* __restrict__ cb64,
    float* __restrict__ winv, unsigned char* __restrict__ poslist, int* __restrict__ nposA,
    float* __restrict__ acc) {
  int wv = threadIdx.x >> 6, lane = threadIdx.x & 63;
  int n = blockIdx.x * 4 + wv;
  __shared__ float shh[2];
  if (threadIdx.x == 0) { shh[0] = 0.0f; shh[1] = 0.0f; }
  __syncthreads();

  int tm = load_tmpl(tmap, lane);
  int tr = load_tmpl(traw, lane);
  float xpv = x[n * 64 + perm[lane]];
  uint32_t i = (uint32_t)(n * 64 + lane);

  float um = tf_uniform(km0, km1, i);
  int rank = 0;
#pragma unroll 16
  for (int k = 0; k < 64; k++) {
    float vk = rdlane(um, k);
    rank += (vk < um) || (vk == um && k < lane);
  }
  ull fm = tm ? (1ull << rank) : 0ull;
#pragma unroll
  for (int off = 1; off < 64; off <<= 1) fm |= __shfl_xor(fm, off);

  float ur = tf_uniform(kr0, kr1, i);
  rank = 0;
#pragma unroll 16
  for (int k = 0; k < 64; k++) {
    float vk = rdlane(ur, k);
    rank += (vk < ur) || (vk == ur && k < lane);
  }
  ull fr = tr ? (1ull << rank) : 0ull;
#pragma unroll
  for (int off = 1; off < 64; off <<= 1) fr |= __shfl_xor(fr, off);

  float xmv = ((fm >> lane) & 1ull) ? -xpv : xpv;
  float rfv = ((fr >> lane) & 1ull) ? -xpv : xpv;
  xp[n * 64 + lane] = xpv;
  xm[n * 64 + lane] = xmv;
  ull t64 = __ballot(rfv > 0.0f);
  ull b64v = __ballot(xpv > 0.0f);

  int c1 = y[(size_t)n * NCLS + lane] > 0;
  int c2 = (lane < NCLS - 64) ? (y[(size_t)n * NCLS + 64 + lane] > 0) : 0;
  ull p0 = __ballot(c1);
  ull p1 = __ballot(c2);
  int cnt0 = __popcll(p0);
  float cnt = (float)(cnt0 + __popcll(p1));

  // parallel poslist scatter (ascending class order preserved)
  unsigned char* pl = poslist + (size_t)n * 64;
  ull below = (lane == 0) ? 0ull : (~0ull >> (64 - lane));
  if (c1) pl[__popcll(p0 & below)] = (unsigned char)lane;
  if (c2) pl[cnt0 + __popcll(p1 & below)] = (unsigned char)(64 + lane);

  // hamming contribution
  float px = (float)__popcll(b64v);
  float hsum = 0.0f;
  if (c1) { ull cb = cb64[lane]; hsum += px + (float)__popcll(cb) - 2.0f * (float)__popcll(b64v & cb); }
  if (c2) { ull cb = cb64[64 + lane]; hsum += px + (float)__popcll(cb) - 2.0f * (float)__popcll(b64v & cb); }
#pragma unroll
  for (int off = 1; off < 64; off <<= 1) hsum += __shfl_xor(hsum, off);

  if (lane == 0) {
    targ[n] = t64;
    winv[n] = 1.0f / cnt;
    nposA[n] = cnt0 + __popcll(p1);
    atomicAdd(&shh[0], hsum);
    atomicAdd(&shh[1], cnt);
  }
  __syncthreads();
  if (threadIdx.x == 0) { atomicAdd(&acc[3], shh[0]); atomicAdd(&acc[4], shh[1]); }
}

// ---------------- fused MLP (all-MFMA, single-plane LDS) + loss epilogue ----
// grid (512, 8, 2); block 256, 4 blocks/CU. pass0 = map (3-term split), pass1 = net.
__global__ __launch_bounds__(256, 4) void mapnet4(
    const float* __restrict__ Xm, const float* __restrict__ Xp,
    const ushort* __restrict__ Wp1, const float* __restrict__ B1,
    const ushort* __restrict__ Wp, const float* __restrict__ B2,
    const ull* __restrict__ targ, const float* __restrict__ winv,
    const unsigned char* __restrict__ poslist, const int* __restrict__ nposA,
    const ull* __restrict__ cb64, float* __restrict__ accg) {
  __shared__ union {
    ushort h[64 * HSS];        // one bf16 h-plane (hi OR lo), 33.8 KB
    float lg[32 * LGS];        // logit staging (aliases h after K-loop)
  } u;
  const int tid = threadIdx.x, lane = tid & 63, wv = tid >> 6;
  const int q = lane >> 4, lr = lane & 15;
  const int m = blockIdx.y, pass = blockIdx.z;
  const int n0 = blockIdx.x * 64;
  const float* Xin = pass ? Xp : Xm;

  // ---- build af = B-operand of transposed L1 (row = n0+wv*16+lr), persists ----
  bf8 af;
  {
    const float* xsrc = Xin + (size_t)(n0 + wv * 16 + lr) * 64 + m * 8;
    f4 v0 = *(const f4*)xsrc;
    f4 v1 = *(const f4*)(xsrc + 4);
    float vf[8] = {v0.x, v0.y, v0.z, v0.w, v1.x, v1.y, v1.z, v1.w};
#pragma unroll
    for (int j = 0; j < 8; j++) {
      float f = vf[j];
      float hi = bf16val(f);
      float el = (q == 2) ? (f - hi) : hi;
      af[j] = (q == 3) ? (__bf16)0.0f : (__bf16)el;
    }
  }

  // ---- L1 (transposed): z^T = W1frag * af; write selected plane ----
  // lane(q,lr) gets h[row=wv*16+lr][hid=t*16+q*4+reg] -> packed b64 write
  auto l1_write = [&](int plane) {
#pragma unroll
    for (int t = 0; t < 16; t++) {
      bf8 wfrag = *(const bf8*)(Wp1 + ((size_t)(m * 16 + t) * 64 + lane) * 8);
      f4 z = __builtin_amdgcn_mfma_f32_16x16x32_bf16(wfrag, af, (f4){0.f, 0.f, 0.f, 0.f}, 0, 0, 0);
      f4 b1v = *(const f4*)(B1 + m * 256 + t * 16 + q * 4);
      us4 pk;
#pragma unroll
      for (int reg = 0; reg < 4; reg++) {
        float zz = z[reg] + b1v[reg];
        float h = zz / (1.0f + __expf(-zz));
        pk[reg] = plane ? bf16bits(h - bf16val(h)) : bf16bits(h);
      }
      *(us4*)(u.h + (size_t)(wv * 16 + lr) * HSS + t * 16 + q * 4) = pk;
    }
  };

  l1_write(0);
  __syncthreads();

  // ---- K loop. wave wv owns cols wv*64..+63; acc[rt][nt] over 64 rows ----
  f4 acc4[4][4];
#pragma unroll
  for (int rt = 0; rt < 4; rt++)
#pragma unroll
    for (int nt = 0; nt < 4; nt++) acc4[rt][nt] = (f4){0.f, 0.f, 0.f, 0.f};

  const size_t wbase = (size_t)m * 8 * 16 * 64 * 8;

  // phase A: ah*bh (+ ah*bl for pass0)
#pragma unroll 2
  for (int kt = 0; kt < 8; kt++) {
    bf8 ah[4];
#pragma unroll
    for (int rt = 0; rt < 4; rt++)
      ah[rt] = *(const bf8*)(u.h + (rt * 16 + lr) * HSS + kt * 32 + q * 8);
#pragma unroll
    for (int nt = 0; nt < 4; nt++) {
      const ushort* bp = Wp + wbase + (((size_t)kt * 16 + (wv * 4 + nt)) * 64 + lane) * 8;
      bf8 bh = *(const bf8*)bp;
      if (pass == 0) {
        bf8 bl = *(const bf8*)(bp + (1 << 19));
#pragma unroll
        for (int rt = 0; rt < 4; rt++) {
          acc4[rt][nt] = __builtin_amdgcn_mfma_f32_16x16x32_bf16(ah[rt], bh, acc4[rt][nt], 0, 0, 0);
          acc4[rt][nt] = __builtin_amdgcn_mfma_f32_16x16x32_bf16(ah[rt], bl, acc4[rt][nt], 0, 0, 0);
        }
      } else {
#pragma unroll
        for (int rt = 0; rt < 4; rt++)
          acc4[rt][nt] = __builtin_amdgcn_mfma_f32_16x16x32_bf16(ah[rt], bh, acc4[rt][nt], 0, 0, 0);
      }
    }
  }

  // phase B (pass0 only): rewrite plane with lo, al*bh
  if (pass == 0) {
    __syncthreads();
    l1_write(1);
    __syncthreads();
#pragma unroll 2
    for (int kt = 0; kt < 8; kt++) {
      bf8 al[4];
#pragma unroll
      for (int rt = 0; rt < 4; rt++)
        al[rt] = *(const bf8*)(u.h + (rt * 16 + lr) * HSS + kt * 32 + q * 8);
#pragma unroll
      for (int nt = 0; nt < 4; nt++) {
        const ushort* bp = Wp + wbase + (((size_t)kt * 16 + (wv * 4 + nt)) * 64 + lane) * 8;
        bf8 bh = *(const bf8*)bp;
#pragma unroll
        for (int rt = 0; rt < 4; rt++)
          acc4[rt][nt] = __builtin_amdgcn_mfma_f32_16x16x32_bf16(al[rt], bh, acc4[rt][nt], 0, 0, 0);
      }
    }
  }

  float bv[4];
#pragma unroll
  for (int nt = 0; nt < 4; nt++) bv[nt] = B2[m * 256 + wv * 64 + nt * 16 + lr];

  // ---- epilogue: two 32-row phases through LDS, vectorized reads ----
  float partLoss = 0.0f, partHit = 0.0f;
  for (int ph = 0; ph < 2; ph++) {
    __syncthreads();
#pragma unroll
    for (int rt2 = 0; rt2 < 2; rt2++) {
      int rt = ph * 2 + rt2;
#pragma unroll
      for (int nt = 0; nt < 4; nt++)
#pragma unroll
        for (int reg = 0; reg < 4; reg++) {
          int row = rt2 * 16 + q * 4 + reg;
          u.lg[row * LGS + wv * 64 + nt * 16 + lr] = acc4[rt][nt][reg] + bv[nt];
        }
    }
    __syncthreads();
    int rl = wv * 8 + (lane >> 3);       // local row 0..31
    int n = n0 + ph * 32 + rl;
    int cj = lane & 7;                   // 8 lanes per row; lane cj owns cols cj*4 + 32k + e
    const float* lrow = u.lg + rl * LGS;
    f4 vv[8];
#pragma unroll
    for (int k = 0; k < 8; k++) vv[k] = *(const f4*)(lrow + cj * 4 + k * 32);
    if (pass == 0) {
      float mv = -1e30f; int mi = 0;
#pragma unroll
      for (int k = 0; k < 8; k++)
#pragma unroll
        for (int e = 0; e < 4; e++) {
          float v = vv[k][e];
          int c = cj * 4 + k * 32 + e;
          if (v > mv) { mv = v; mi = c; }
        }
#pragma unroll
      for (int off = 1; off < 8; off <<= 1) {
        float om = __shfl_xor(mv, off); int oi = __shfl_xor(mi, off);
        if (om > mv || (om == mv && oi < mi)) { mv = om; mi = oi; }
      }
      float s = 0.0f;
#pragma unroll
      for (int k = 0; k < 8; k++)
#pragma unroll
        for (int e = 0; e < 4; e++) s += __expf(vv[k][e] - mv);
#pragma unroll
      for (int off = 1; off < 8; off <<= 1) s += __shfl_xor(s, off);
      if (cj == 0) {
        float lse = mv + __logf(s);
        int t = (int)((targ[n] >> (m * 8)) & 0xFFull);
        partLoss += lse - lrow[t];
        partHit += (mi == t) ? 1.0f : 0.0f;
      }
    } else {
      float s = 0.0f;
#pragma unroll
      for (int k = 0; k < 8; k++)
#pragma unroll
        for (int e = 0; e < 4; e++) s += __expf(vv[k][e]);
#pragma unroll
      for (int off = 1; off < 8; off <<= 1) s += __shfl_xor(s, off);
      int np = nposA[n];
      const unsigned char* pl = poslist + (size_t)n * 64;
      float sp = 0.0f;
      for (int j2 = cj; j2 < np; j2 += 8) {
        int c = pl[j2];
        int t = (int)((cb64[c] >> (m * 8)) & 0xFFull);
        sp += lrow[t];
      }
#pragma unroll
      for (int off = 1; off < 8; off <<= 1) sp += __shfl_xor(sp, off);
      if (cj == 0) partLoss += __logf(s) - winv[n] * sp;
    }
  }
#pragma unroll
  for (int off = 1; off < 64; off <<= 1) {
    partLoss += __shfl_xor(partLoss, off);
    partHit += __shfl_xor(partHit, off);
  }
  if (lane == 0) {
    if (pass == 0) { atomicAdd(&accg[0], partLoss); atomicAdd(&accg[2], partHit); }
    else           { atomicAdd(&accg[1], partLoss); }
  }
}

__global__ void finalk(const float* __restrict__ acc, float* __restrict__ out) {
  float netLoss = acc[1] / (float)NR;
  float mapLoss = acc[0] / (float)NR;
  out[0] = netLoss + mapLoss;
  out[1] = netLoss;
  out[2] = mapLoss;
  out[3] = acc[2] / (float)(NR * MM);
  out[4] = acc[3] / acc[4];
}

extern "C" void kernel_launch(void* const* d_in, const int* in_sizes, int n_in,
                              void* d_out, int out_size, void* d_ws, size_t ws_size,
                              hipStream_t stream) {
  const float* x = (const float*)d_in[0];
  const int* y = (const int*)d_in[1];
  const float* centroids = (const float*)d_in[2];
  const int* perm = (const int*)d_in[3];
  const void* tmap = d_in[4];
  const void* traw = d_in[5];
  const float* W1 = (const float*)d_in[6];
  const float* B1 = (const float*)d_in[7];
  const float* W2 = (const float*)d_in[8];
  const float* B2 = (const float*)d_in[9];
  float* out = (float*)d_out;

  char* w = (char*)d_ws;
  float* acc = (float*)w;                                     // 256 B reserved
  float* xp = (float*)(w + 256);                              // 8 MB
  float* xm = xp + (size_t)NR * 64;                           // 8 MB
  ull* targ = (ull*)(xm + (size_t)NR * 64);                   // 256 KB
  ull* cb64 = targ + NR;                                      // 1 KB (128 slots)
  float* winv = (float*)(cb64 + 128);                         // 128 KB
  int* nposA = (int*)(winv + NR);                             // 128 KB
  unsigned char* poslist = (unsigned char*)(nposA + NR);      // 2 MB
  ushort* Wp = (ushort*)(poslist + (size_t)NR * 64);          // 2 MB (hi + lo)
  ushort* Wp1 = Wp + (1 << 20);                               // 128 KB (L1 frags)

  hipMemsetAsync(acc, 0, 64, stream);

  // jax.random.key(1) -> (0,1); split -> kmap=(w0(0,2), w0(1,3)), kraw=(w1(0,2), w1(1,3))
  uint32_t a0, b0, a1, b1;
  tf2x32(0u, 1u, 0u, 2u, a0, b0);
  tf2x32(0u, 1u, 1u, 3u, a1, b1);

  packW2<<<256, 256, 0, stream>>>(W2, Wp);
  packW1<<<32, 256, 0, stream>>>(W1, Wp1);
  stage2<<<1, 128, 0, stream>>>(centroids, perm, cb64);
  stage1<<<NR / 4, 256, 0, stream>>>(x, y, perm, tmap, traw, a0, a1, b0, b1,
                                     xp, xm, targ, cb64, winv, poslist, nposA, acc);
  dim3 g(NR / 64, MM, 2);
  mapnet4<<<g, 256, 0, stream>>>(xm, xp, Wp1, B1, Wp, B2, targ, winv, poslist, nposA, cb64, acc);
  finalk<<<1, 1, 0, stream>>>(acc, out);
}

// Round 5
// 956.567 us; speedup vs baseline: 1.0800x; 1.0663x over previous
//
#include <hip/hip_runtime.h>
#include <stdint.h>

#define NR 32768
#define MM 8
#define NCLS 100
#define HALFN 1048576u
#define HSS 260   // fp16 stride for h plane rows: 130 words == 2 mod 4 -> balanced banks
#define LGS 260   // float stride for logit rows

typedef _Float16 h8 __attribute__((ext_vector_type(8)));
typedef _Float16 h4 __attribute__((ext_vector_type(4)));
typedef float f4 __attribute__((ext_vector_type(4)));
typedef unsigned long long ull;

// ---------------- threefry2x32 (exact JAX semantics) ----------------
__host__ __device__ inline void tf2x32(uint32_t k0, uint32_t k1, uint32_t x0, uint32_t x1,
                                       uint32_t& o0, uint32_t& o1) {
  uint32_t ks0 = k0, ks1 = k1, ks2 = k0 ^ k1 ^ 0x1BD11BDAu;
  x0 += ks0; x1 += ks1;
#define TFR(r) { x0 += x1; x1 = (x1 << r) | (x1 >> (32 - r)); x1 ^= x0; }
  TFR(13) TFR(15) TFR(26) TFR(6)  x0 += ks1; x1 += ks2 + 1u;
  TFR(17) TFR(29) TFR(16) TFR(24) x0 += ks2; x1 += ks0 + 2u;
  TFR(13) TFR(15) TFR(26) TFR(6)  x0 += ks0; x1 += ks1 + 3u;
  TFR(17) TFR(29) TFR(16) TFR(24) x0 += ks1; x1 += ks2 + 4u;
  TFR(13) TFR(15) TFR(26) TFR(6)  x0 += ks2; x1 += ks0 + 5u;
#undef TFR
  o0 = x0; o1 = x1;
}

__device__ inline float tf_uniform(uint32_t k0, uint32_t k1, uint32_t i) {
  uint32_t o0, o1, b;
  if (i < HALFN) { tf2x32(k0, k1, i, i + HALFN, o0, o1); b = o0; }
  else           { tf2x32(k0, k1, i - HALFN, i, o0, o1); b = o1; }
  return __uint_as_float((b >> 9) | 0x3F800000u) - 1.0f;
}

// template dtype auto-detect: float32 {0,1.0f} / int32 {0,1} / bytes. 4 ones expected.
__device__ inline int load_tmpl(const void* p, int lane) {
  const unsigned* pi = (const unsigned*)p;
  unsigned w = pi[lane];
  ull okF = __ballot(w == 0u || w == 0x3F800000u);
  ull onF = __ballot(w == 0x3F800000u);
  ull okI = __ballot(w <= 1u);
  ull onI = __ballot(w == 1u);
  if (okF == ~0ull && __popcll(onF) == 4) return (w == 0x3F800000u) ? 1 : 0;
  if (okI == ~0ull && __popcll(onI) == 4) return (int)w;
  const unsigned char* pb = (const unsigned char*)p;
  return pb[lane] ? 1 : 0;
}

__device__ inline float rdlane(float v, int l) {
  return __int_as_float(__builtin_amdgcn_readlane(__float_as_int(v), l));
}

// ---------------- pack W2 into MFMA B-fragment order, fp16 ----------
// gid = ((m*8+kt)*16+NT)*64 + q*16+lr ; element j = W2[m][kt*32+q*8+j][NT*16+lr]
__global__ __launch_bounds__(256) void packW2(const float* __restrict__ W2, _Float16* __restrict__ Wp) {
  int gid = blockIdx.x * 256 + threadIdx.x;          // 65536 total
  int lane6 = gid & 63, frag = gid >> 6;
  int NT = frag & 15, kt = (frag >> 4) & 7, m = frag >> 7;
  int q = lane6 >> 4, lr = lane6 & 15;
  const float* src = W2 + (size_t)m * 65536 + (size_t)(kt * 32 + q * 8) * 256 + NT * 16 + lr;
  h8 v;
#pragma unroll
  for (int j = 0; j < 8; j++) v[j] = (_Float16)src[j * 256];
  *(h8*)(Wp + (size_t)gid * 8) = v;
}

// ---------------- pack W1 frags (A-operand of transposed L1) ------
// frag (m, t): lane(q,lr) j -> A[hid=t*16+lr][k=q*8+j]: q0 = W1[j][hid], else 0
__global__ __launch_bounds__(256) void packW1(const float* __restrict__ W1, _Float16* __restrict__ Wp1) {
  int idx = blockIdx.x * 256 + threadIdx.x;  // (m, t, lane): 8*16*64 = 8192
  int lane = idx & 63, t = (idx >> 6) & 15, m = idx >> 10;
  int q = lane >> 4, lr = lane & 15;
  h8 v;
#pragma unroll
  for (int j = 0; j < 8; j++)
    v[j] = (q == 0) ? (_Float16)W1[(size_t)(m * 8 + j) * 256 + t * 16 + lr] : (_Float16)0.0f;
  *(h8*)(Wp1 + (size_t)idx * 8) = v;
}

// ---------------- stage2: centroid bits ----------------
__global__ void stage2(const float* __restrict__ centroids, const int* __restrict__ perm,
                       ull* __restrict__ cb64) {
  int c = threadIdx.x;
  if (c >= 128) return;
  ull bits = 0;
  if (c < NCLS)
    for (int j = 0; j < 64; j++)
      if (centroids[c * 64 + perm[j]] > 0.0f) bits |= (1ull << j);
  cb64[c] = bits;
}

// ---------------- stage1: permute, flips, targets, y scan, hamming -----------
__global__ __launch_bounds__(256) void stage1(
    const float* __restrict__ x, const int* __restrict__ y, const int* __restrict__ perm,
    const void* tmap, const void* traw,
    uint32_t km0, uint32_t km1, uint32_t kr0, uint32_t kr1,
    float* __restrict__ xp, float* __restrict__ xm,
    ull* __restrict__ targ, const ull* __restrict__ cb64,
    float* __restrict__ winv, unsigned char* __restrict__ poslist, int* __restrict__ nposA,
    float* __restrict__ acc) {
  int wv = threadIdx.x >> 6, lane = threadIdx.x & 63;
  int n = blockIdx.x * 4 + wv;
  __shared__ float shh[2];
  if (threadIdx.x == 0) { shh[0] = 0.0f; shh[1] = 0.0f; }
  __syncthreads();

  int tm = load_tmpl(tmap, lane);
  int tr = load_tmpl(traw, lane);
  float xpv = x[n * 64 + perm[lane]];
  uint32_t i = (uint32_t)(n * 64 + lane);

  float um = tf_uniform(km0, km1, i);
  int rank = 0;
#pragma unroll 16
  for (int k = 0; k < 64; k++) {
    float vk = rdlane(um, k);
    rank += (vk < um) || (vk == um && k < lane);
  }
  ull fm = tm ? (1ull << rank) : 0ull;
#pragma unroll
  for (int off = 1; off < 64; off <<= 1) fm |= __shfl_xor(fm, off);

  float ur = tf_uniform(kr0, kr1, i);
  rank = 0;
#pragma unroll 16
  for (int k = 0; k < 64; k++) {
    float vk = rdlane(ur, k);
    rank += (vk < ur) || (vk == ur && k < lane);
  }
  ull fr = tr ? (1ull << rank) : 0ull;
#pragma unroll
  for (int off = 1; off < 64; off <<= 1) fr |= __shfl_xor(fr, off);

  float xmv = ((fm >> lane) & 1ull) ? -xpv : xpv;
  float rfv = ((fr >> lane) & 1ull) ? -xpv : xpv;
  xp[n * 64 + lane] = xpv;
  xm[n * 64 + lane] = xmv;
  ull t64 = __ballot(rfv > 0.0f);
  ull b64v = __ballot(xpv > 0.0f);

  int c1 = y[(size_t)n * NCLS + lane] > 0;
  int c2 = (lane < NCLS - 64) ? (y[(size_t)n * NCLS + 64 + lane] > 0) : 0;
  ull p0 = __ballot(c1);
  ull p1 = __ballot(c2);
  int cnt0 = __popcll(p0);
  float cnt = (float)(cnt0 + __popcll(p1));

  // parallel poslist scatter (ascending class order preserved)
  unsigned char* pl = poslist + (size_t)n * 64;
  ull below = (lane == 0) ? 0ull : (~0ull >> (64 - lane));
  if (c1) pl[__popcll(p0 & below)] = (unsigned char)lane;
  if (c2) pl[cnt0 + __popcll(p1 & below)] = (unsigned char)(64 + lane);

  // hamming contribution
  float px = (float)__popcll(b64v);
  float hsum = 0.0f;
  if (c1) { ull cb = cb64[lane]; hsum += px + (float)__popcll(cb) - 2.0f * (float)__popcll(b64v & cb); }
  if (c2) { ull cb = cb64[64 + lane]; hsum += px + (float)__popcll(cb) - 2.0f * (float)__popcll(b64v & cb); }
#pragma unroll
  for (int off = 1; off < 64; off <<= 1) hsum += __shfl_xor(hsum, off);

  if (lane == 0) {
    targ[n] = t64;
    winv[n] = 1.0f / cnt;
    nposA[n] = cnt0 + __popcll(p1);
    atomicAdd(&shh[0], hsum);
    atomicAdd(&shh[1], cnt);
  }
  __syncthreads();
  if (threadIdx.x == 0) { atomicAdd(&acc[3], shh[0]); atomicAdd(&acc[4], shh[1]); }
}

// ---------------- fused MLP (fp16 MFMA, single plane) + loss epilogue ----
// grid (512, 8, 2); block 256, 4 blocks/CU. pass0 = map, pass1 = net.
__global__ __launch_bounds__(256, 4) void mapnet5(
    const float* __restrict__ Xm, const float* __restrict__ Xp,
    const _Float16* __restrict__ Wp1, const float* __restrict__ B1,
    const _Float16* __restrict__ Wp, const float* __restrict__ B2,
    const ull* __restrict__ targ, const float* __restrict__ winv,
    const unsigned char* __restrict__ poslist, const int* __restrict__ nposA,
    const ull* __restrict__ cb64, float* __restrict__ accg) {
  __shared__ union {
    _Float16 h[64 * HSS];      // fp16 h-plane, 33.3 KB
    float lg[32 * LGS];        // logit staging (aliases h after K-loop)
  } u;
  const int tid = threadIdx.x, lane = tid & 63, wv = tid >> 6;
  const int q = lane >> 4, lr = lane & 15;
  const int m = blockIdx.y, pass = blockIdx.z;
  const int n0 = blockIdx.x * 64;
  const float* Xin = pass ? Xp : Xm;

  // ---- af = B-operand of transposed L1 (col = row n0+wv*16+lr, k=q*8+j: q0=x else 0)
  h8 af;
  {
    const float* xsrc = Xin + (size_t)(n0 + wv * 16 + lr) * 64 + m * 8;
    f4 v0 = *(const f4*)xsrc;
    f4 v1 = *(const f4*)(xsrc + 4);
    float vf[8] = {v0.x, v0.y, v0.z, v0.w, v1.x, v1.y, v1.z, v1.w};
#pragma unroll
    for (int j = 0; j < 8; j++) af[j] = (q == 0) ? (_Float16)vf[j] : (_Float16)0.0f;
  }

  // ---- L1 (transposed): z^T = W1frag * af -> lane(q,lr) owns h[row=wv*16+lr][t*16+q*4..+3]
#pragma unroll 4
  for (int t = 0; t < 16; t++) {
    h8 wfrag = *(const h8*)(Wp1 + ((size_t)(m * 16 + t) * 64 + lane) * 8);
    f4 z = __builtin_amdgcn_mfma_f32_16x16x32_f16(wfrag, af, (f4){0.f, 0.f, 0.f, 0.f}, 0, 0, 0);
    f4 b1v = *(const f4*)(B1 + m * 256 + t * 16 + q * 4);
    h4 pk;
#pragma unroll
    for (int reg = 0; reg < 4; reg++) {
      float zz = z[reg] + b1v[reg];
      pk[reg] = (_Float16)(zz / (1.0f + __expf(-zz)));
    }
    *(h4*)(u.h + (size_t)(wv * 16 + lr) * HSS + t * 16 + q * 4) = pk;
  }
  __syncthreads();

  // ---- K loop. wave wv owns cols wv*64..+63; acc[rt][nt] over 64 rows ----
  f4 acc4[4][4];
#pragma unroll
  for (int rt = 0; rt < 4; rt++)
#pragma unroll
    for (int nt = 0; nt < 4; nt++) acc4[rt][nt] = (f4){0.f, 0.f, 0.f, 0.f};

  const size_t wbase = (size_t)m * 65536;
#pragma unroll 2
  for (int kt = 0; kt < 8; kt++) {
    h8 ah[4];
#pragma unroll
    for (int rt = 0; rt < 4; rt++) {
      const _Float16* p = u.h + (rt * 16 + lr) * HSS + kt * 32 + q * 8;
      h4 lo = *(const h4*)p;
      h4 hi = *(const h4*)(p + 4);
      ah[rt] = __builtin_shufflevector(lo, hi, 0, 1, 2, 3, 4, 5, 6, 7);
    }
#pragma unroll
    for (int nt = 0; nt < 4; nt++) {
      h8 bh = *(const h8*)(Wp + wbase + (((size_t)kt * 16 + (wv * 4 + nt)) * 64 + lane) * 8);
#pragma unroll
      for (int rt = 0; rt < 4; rt++)
        acc4[rt][nt] = __builtin_amdgcn_mfma_f32_16x16x32_f16(ah[rt], bh, acc4[rt][nt], 0, 0, 0);
    }
  }

  float bv[4];
#pragma unroll
  for (int nt = 0; nt < 4; nt++) bv[nt] = B2[m * 256 + wv * 64 + nt * 16 + lr];

  // ---- epilogue: two 32-row phases through LDS, vectorized reads ----
  float partLoss = 0.0f, partHit = 0.0f;
  for (int ph = 0; ph < 2; ph++) {
    __syncthreads();
#pragma unroll
    for (int rt2 = 0; rt2 < 2; rt2++) {
      int rt = ph * 2 + rt2;
#pragma unroll
      for (int nt = 0; nt < 4; nt++)
#pragma unroll
        for (int reg = 0; reg < 4; reg++) {
          int row = rt2 * 16 + q * 4 + reg;
          u.lg[row * LGS + wv * 64 + nt * 16 + lr] = acc4[rt][nt][reg] + bv[nt];
        }
    }
    __syncthreads();
    int rl = wv * 8 + (lane >> 3);       // local row 0..31
    int n = n0 + ph * 32 + rl;
    int cj = lane & 7;                   // 8 lanes per row; lane cj owns cols cj*4 + 32k + e
    const float* lrow = u.lg + rl * LGS;
    f4 vv[8];
#pragma unroll
    for (int k = 0; k < 8; k++) vv[k] = *(const f4*)(lrow + cj * 4 + k * 32);
    if (pass == 0) {
      float mv = -1e30f; int mi = 0;
#pragma unroll
      for (int k = 0; k < 8; k++)
#pragma unroll
        for (int e = 0; e < 4; e++) {
          float v = vv[k][e];
          int c = cj * 4 + k * 32 + e;
          if (v > mv) { mv = v; mi = c; }
        }
#pragma unroll
      for (int off = 1; off < 8; off <<= 1) {
        float om = __shfl_xor(mv, off); int oi = __shfl_xor(mi, off);
        if (om > mv || (om == mv && oi < mi)) { mv = om; mi = oi; }
      }
      float s = 0.0f;
#pragma unroll
      for (int k = 0; k < 8; k++)
#pragma unroll
        for (int e = 0; e < 4; e++) s += __expf(vv[k][e] - mv);
#pragma unroll
      for (int off = 1; off < 8; off <<= 1) s += __shfl_xor(s, off);
      if (cj == 0) {
        float lse = mv + __logf(s);
        int t = (int)((targ[n] >> (m * 8)) & 0xFFull);
        partLoss += lse - lrow[t];
        partHit += (mi == t) ? 1.0f : 0.0f;
      }
    } else {
      float s = 0.0f;
#pragma unroll
      for (int k = 0; k < 8; k++)
#pragma unroll
        for (int e = 0; e < 4; e++) s += __expf(vv[k][e]);
#pragma unroll
      for (int off = 1; off < 8; off <<= 1) s += __shfl_xor(s, off);
      int np = nposA[n];
      const unsigned char* pl = poslist + (size_t)n * 64;
      float sp = 0.0f;
      for (int j2 = cj; j2 < np; j2 += 8) {
        int c = pl[j2];
        int t = (int)((cb64[c] >> (m * 8)) & 0xFFull);
        sp += lrow[t];
      }
#pragma unroll
      for (int off = 1; off < 8; off <<= 1) sp += __shfl_xor(sp, off);
      if (cj == 0) partLoss += __logf(s) - winv[n] * sp;
    }
  }
#pragma unroll
  for (int off = 1; off < 64; off <<= 1) {
    partLoss += __shfl_xor(partLoss, off);
    partHit += __shfl_xor(partHit, off);
  }
  if (lane == 0) {
    if (pass == 0) { atomicAdd(&accg[0], partLoss); atomicAdd(&accg[2], partHit); }
    else           { atomicAdd(&accg[1], partLoss); }
  }
}

__global__ void finalk(const float* __restrict__ acc, float* __restrict__ out) {
  float netLoss = acc[1] / (float)NR;
  float mapLoss = acc[0] / (float)NR;
  out[0] = netLoss + mapLoss;
  out[1] = netLoss;
  out[2] = mapLoss;
  out[3] = acc[2] / (float)(NR * MM);
  out[4] = acc[3] / acc[4];
}

extern "C" void kernel_launch(void* const* d_in, const int* in_sizes, int n_in,
                              void* d_out, int out_size, void* d_ws, size_t ws_size,
                              hipStream_t stream) {
  const float* x = (const float*)d_in[0];
  const int* y = (const int*)d_in[1];
  const float* centroids = (const float*)d_in[2];
  const int* perm = (const int*)d_in[3];
  const void* tmap = d_in[4];
  const void* traw = d_in[5];
  const float* W1 = (const float*)d_in[6];
  const float* B1 = (const float*)d_in[7];
  const float* W2 = (const float*)d_in[8];
  const float* B2 = (const float*)d_in[9];
  float* out = (float*)d_out;

  char* w = (char*)d_ws;
  float* acc = (float*)w;                                     // 256 B reserved
  float* xp = (float*)(w + 256);                              // 8 MB
  float* xm = xp + (size_t)NR * 64;                           // 8 MB
  ull* targ = (ull*)(xm + (size_t)NR * 64);                   // 256 KB
  ull* cb64 = targ + NR;                                      // 1 KB (128 slots)
  float* winv = (float*)(cb64 + 128);                         // 128 KB
  int* nposA = (int*)(winv + NR);                             // 128 KB
  unsigned char* poslist = (unsigned char*)(nposA + NR);      // 2 MB
  _Float16* Wp = (_Float16*)(poslist + (size_t)NR * 64);      // 1 MB (fp16 frags)
  _Float16* Wp1 = Wp + (1 << 19);                             // 128 KB (L1 frags)

  hipMemsetAsync(acc, 0, 64, stream);

  // jax.random.key(1) -> (0,1); split -> kmap=(w0(0,2), w0(1,3)), kraw=(w1(0,2), w1(1,3))
  uint32_t a0, b0, a1, b1;
  tf2x32(0u, 1u, 0u, 2u, a0, b0);
  tf2x32(0u, 1u, 1u, 3u, a1, b1);

  packW2<<<256, 256, 0, stream>>>(W2, Wp);
  packW1<<<32, 256, 0, stream>>>(W1, Wp1);
  stage2<<<1, 128, 0, stream>>>(centroids, perm, cb64);
  stage1<<<NR / 4, 256, 0, stream>>>(x, y, perm, tmap, traw, a0, a1, b0, b1,
                                     xp, xm, targ, cb64, winv, poslist, nposA, acc);
  dim3 g(NR / 64, MM, 2);
  mapnet5<<<g, 256, 0, stream>>>(xm, xp, Wp1, B1, Wp, B2, targ, winv, poslist, nposA, cb64, acc);
  finalk<<<1, 1, 0, stream>>>(acc, out);
}

// Round 6
// 313.394 us; speedup vs baseline: 3.2964x; 3.0523x over previous
//
#include <hip/hip_runtime.h>
#include <stdint.h>

#define NR 32768
#define MM 8
#define NCLS 100
#define HALFN 1048576u
#define HSS 260   // fp16 stride for h plane rows: balanced banks for b64 frag reads
#define LGS 260   // float stride for logit rows

typedef _Float16 h8 __attribute__((ext_vector_type(8)));
typedef _Float16 h4 __attribute__((ext_vector_type(4)));
typedef float f4 __attribute__((ext_vector_type(4)));
typedef unsigned long long ull;

// ---------------- threefry2x32 (exact JAX semantics) ----------------
__host__ __device__ inline void tf2x32(uint32_t k0, uint32_t k1, uint32_t x0, uint32_t x1,
                                       uint32_t& o0, uint32_t& o1) {
  uint32_t ks0 = k0, ks1 = k1, ks2 = k0 ^ k1 ^ 0x1BD11BDAu;
  x0 += ks0; x1 += ks1;
#define TFR(r) { x0 += x1; x1 = (x1 << r) | (x1 >> (32 - r)); x1 ^= x0; }
  TFR(13) TFR(15) TFR(26) TFR(6)  x0 += ks1; x1 += ks2 + 1u;
  TFR(17) TFR(29) TFR(16) TFR(24) x0 += ks2; x1 += ks0 + 2u;
  TFR(13) TFR(15) TFR(26) TFR(6)  x0 += ks0; x1 += ks1 + 3u;
  TFR(17) TFR(29) TFR(16) TFR(24) x0 += ks1; x1 += ks2 + 4u;
  TFR(13) TFR(15) TFR(26) TFR(6)  x0 += ks2; x1 += ks0 + 5u;
#undef TFR
  o0 = x0; o1 = x1;
}

__device__ inline float tf_uniform(uint32_t k0, uint32_t k1, uint32_t i) {
  uint32_t o0, o1, b;
  if (i < HALFN) { tf2x32(k0, k1, i, i + HALFN, o0, o1); b = o0; }
  else           { tf2x32(k0, k1, i - HALFN, i, o0, o1); b = o1; }
  return __uint_as_float((b >> 9) | 0x3F800000u) - 1.0f;
}

// template dtype auto-detect: float32 {0,1.0f} / int32 {0,1} / bytes. 4 ones expected.
__device__ inline int load_tmpl(const void* p, int lane) {
  const unsigned* pi = (const unsigned*)p;
  unsigned w = pi[lane];
  ull okF = __ballot(w == 0u || w == 0x3F800000u);
  ull onF = __ballot(w == 0x3F800000u);
  ull okI = __ballot(w <= 1u);
  ull onI = __ballot(w == 1u);
  if (okF == ~0ull && __popcll(onF) == 4) return (w == 0x3F800000u) ? 1 : 0;
  if (okI == ~0ull && __popcll(onI) == 4) return (int)w;
  const unsigned char* pb = (const unsigned char*)p;
  return pb[lane] ? 1 : 0;
}

__device__ inline float rdlane(float v, int l) {
  return __int_as_float(__builtin_amdgcn_readlane(__float_as_int(v), l));
}

// ---------------- pack W2 into MFMA B-fragment order, fp16 ----------
// gid = ((m*8+kt)*16+NT)*64 + q*16+lr ; element j = W2[m][kt*32+q*8+j][NT*16+lr]
__global__ __launch_bounds__(256) void packW2(const float* __restrict__ W2, _Float16* __restrict__ Wp) {
  int gid = blockIdx.x * 256 + threadIdx.x;          // 65536 total
  int lane6 = gid & 63, frag = gid >> 6;
  int NT = frag & 15, kt = (frag >> 4) & 7, m = frag >> 7;
  int q = lane6 >> 4, lr = lane6 & 15;
  const float* src = W2 + (size_t)m * 65536 + (size_t)(kt * 32 + q * 8) * 256 + NT * 16 + lr;
  h8 v;
#pragma unroll
  for (int j = 0; j < 8; j++) v[j] = (_Float16)src[j * 256];
  *(h8*)(Wp + (size_t)gid * 8) = v;
}

// ---------------- pack W1 frags (A-operand of transposed L1) ------
// frag (m, t): lane(q,lr) j -> A[hid=t*16+lr][k=q*8+j]: q0 = W1[j][hid], else 0
__global__ __launch_bounds__(256) void packW1(const float* __restrict__ W1, _Float16* __restrict__ Wp1) {
  int idx = blockIdx.x * 256 + threadIdx.x;  // (m, t, lane): 8*16*64 = 8192
  int lane = idx & 63, t = (idx >> 6) & 15, m = idx >> 10;
  int q = lane >> 4, lr = lane & 15;
  h8 v;
#pragma unroll
  for (int j = 0; j < 8; j++)
    v[j] = (q == 0) ? (_Float16)W1[(size_t)(m * 8 + j) * 256 + t * 16 + lr] : (_Float16)0.0f;
  *(h8*)(Wp1 + (size_t)idx * 8) = v;
}

// ---------------- stage2: centroid bits ----------------
__global__ void stage2(const float* __restrict__ centroids, const int* __restrict__ perm,
                       ull* __restrict__ cb64) {
  int c = threadIdx.x;
  if (c >= 128) return;
  ull bits = 0;
  if (c < NCLS)
    for (int j = 0; j < 64; j++)
      if (centroids[c * 64 + perm[j]] > 0.0f) bits |= (1ull << j);
  cb64[c] = bits;
}

// ---------------- stage1: permute, flips, targets, y scan, hamming -----------
__global__ __launch_bounds__(256) void stage1(
    const float* __restrict__ x, const int* __restrict__ y, const int* __restrict__ perm,
    const void* tmap, const void* traw,
    uint32_t km0, uint32_t km1, uint32_t kr0, uint32_t kr1,
    float* __restrict__ xp, float* __restrict__ xm,
    ull* __restrict__ targ, const ull* __restrict__ cb64,
    float* __restrict__ winv, unsigned char* __restrict__ poslist, int* __restrict__ nposA,
    float* __restrict__ accbuf) {
  int wv = threadIdx.x >> 6, lane = threadIdx.x & 63;
  int n = blockIdx.x * 4 + wv;
  __shared__ float shh[2];
  if (threadIdx.x == 0) { shh[0] = 0.0f; shh[1] = 0.0f; }
  __syncthreads();

  int tm = load_tmpl(tmap, lane);
  int tr = load_tmpl(traw, lane);
  float xpv = x[n * 64 + perm[lane]];
  uint32_t i = (uint32_t)(n * 64 + lane);

  float um = tf_uniform(km0, km1, i);
  int rank = 0;
#pragma unroll 16
  for (int k = 0; k < 64; k++) {
    float vk = rdlane(um, k);
    rank += (vk < um) || (vk == um && k < lane);
  }
  ull fm = tm ? (1ull << rank) : 0ull;
#pragma unroll
  for (int off = 1; off < 64; off <<= 1) fm |= __shfl_xor(fm, off);

  float ur = tf_uniform(kr0, kr1, i);
  rank = 0;
#pragma unroll 16
  for (int k = 0; k < 64; k++) {
    float vk = rdlane(ur, k);
    rank += (vk < ur) || (vk == ur && k < lane);
  }
  ull fr = tr ? (1ull << rank) : 0ull;
#pragma unroll
  for (int off = 1; off < 64; off <<= 1) fr |= __shfl_xor(fr, off);

  float xmv = ((fm >> lane) & 1ull) ? -xpv : xpv;
  float rfv = ((fr >> lane) & 1ull) ? -xpv : xpv;
  xp[n * 64 + lane] = xpv;
  xm[n * 64 + lane] = xmv;
  ull t64 = __ballot(rfv > 0.0f);
  ull b64v = __ballot(xpv > 0.0f);

  int c1 = y[(size_t)n * NCLS + lane] > 0;
  int c2 = (lane < NCLS - 64) ? (y[(size_t)n * NCLS + 64 + lane] > 0) : 0;
  ull p0 = __ballot(c1);
  ull p1 = __ballot(c2);
  int cnt0 = __popcll(p0);
  float cnt = (float)(cnt0 + __popcll(p1));

  // parallel poslist scatter (ascending class order preserved)
  unsigned char* pl = poslist + (size_t)n * 64;
  ull below = (lane == 0) ? 0ull : (~0ull >> (64 - lane));
  if (c1) pl[__popcll(p0 & below)] = (unsigned char)lane;
  if (c2) pl[cnt0 + __popcll(p1 & below)] = (unsigned char)(64 + lane);

  // hamming contribution
  float px = (float)__popcll(b64v);
  float hsum = 0.0f;
  if (c1) { ull cb = cb64[lane]; hsum += px + (float)__popcll(cb) - 2.0f * (float)__popcll(b64v & cb); }
  if (c2) { ull cb = cb64[64 + lane]; hsum += px + (float)__popcll(cb) - 2.0f * (float)__popcll(b64v & cb); }
#pragma unroll
  for (int off = 1; off < 64; off <<= 1) hsum += __shfl_xor(hsum, off);

  if (lane == 0) {
    targ[n] = t64;
    winv[n] = 1.0f / cnt;
    nposA[n] = cnt0 + __popcll(p1);
    atomicAdd(&shh[0], hsum);
    atomicAdd(&shh[1], cnt);
  }
  __syncthreads();
  if (threadIdx.x == 0) {
    float* slot = accbuf + (blockIdx.x & 127) * 8;
    atomicAdd(&slot[3], shh[0]);
    atomicAdd(&slot[4], shh[1]);
  }
}

// ---------------- fused MLP (fp16 MFMA, 8-wave blocks) + loss epilogue ----
// grid (512, 8, 2); block 512 (8 waves). pass0 = map, pass1 = net.
// wave wv owns cols wv*32..+31 in the K-loop; L1 split by (rowblock, t-range).
__global__ __launch_bounds__(512, 6) void mapnet6(
    const float* __restrict__ Xm, const float* __restrict__ Xp,
    const _Float16* __restrict__ Wp1, const float* __restrict__ B1,
    const _Float16* __restrict__ Wp, const float* __restrict__ B2,
    const ull* __restrict__ targ, const float* __restrict__ winv,
    const unsigned char* __restrict__ poslist, const int* __restrict__ nposA,
    const ull* __restrict__ cb64, float* __restrict__ accbuf) {
  __shared__ union {
    _Float16 h[64 * HSS];      // fp16 h-plane, 33280 B
    float lg[32 * LGS];        // logit staging, 33280 B (exact alias)
  } u;
  __shared__ float sl[3];      // block loss accumulators
  const int tid = threadIdx.x, lane = tid & 63, wv = tid >> 6;
  const int q = lane >> 4, lr = lane & 15;
  const int m = blockIdx.y, pass = blockIdx.z;
  const int n0 = blockIdx.x * 64;
  const float* Xin = pass ? Xp : Xm;
  if (tid < 3) sl[tid] = 0.0f;

  // ---- L1 (transposed): wave wv covers rowblock rb = wv&3, t-range (wv>>2)*8..+7
  const int rb = wv & 3, tbase = (wv >> 2) * 8;
  h8 af;
  {
    const float* xsrc = Xin + (size_t)(n0 + rb * 16 + lr) * 64 + m * 8;
    f4 v0 = *(const f4*)xsrc;
    f4 v1 = *(const f4*)(xsrc + 4);
    float vf[8] = {v0.x, v0.y, v0.z, v0.w, v1.x, v1.y, v1.z, v1.w};
#pragma unroll
    for (int j = 0; j < 8; j++) af[j] = (q == 0) ? (_Float16)vf[j] : (_Float16)0.0f;
  }
#pragma unroll 4
  for (int tt = 0; tt < 8; tt++) {
    int t = tbase + tt;
    h8 wfrag = *(const h8*)(Wp1 + ((size_t)(m * 16 + t) * 64 + lane) * 8);
    f4 z = __builtin_amdgcn_mfma_f32_16x16x32_f16(wfrag, af, (f4){0.f, 0.f, 0.f, 0.f}, 0, 0, 0);
    f4 b1v = *(const f4*)(B1 + m * 256 + t * 16 + q * 4);
    h4 pk;
#pragma unroll
    for (int reg = 0; reg < 4; reg++) {
      float zz = z[reg] + b1v[reg];
      pk[reg] = (_Float16)(zz / (1.0f + __expf(-zz)));
    }
    *(h4*)(u.h + (size_t)(rb * 16 + lr) * HSS + t * 16 + q * 4) = pk;
  }
  __syncthreads();

  // ---- K loop: wave wv owns cols wv*32 + nt*16 + lr (nt 0..1), 64 rows ----
  f4 acc4[4][2];
#pragma unroll
  for (int rt = 0; rt < 4; rt++)
#pragma unroll
    for (int nt = 0; nt < 2; nt++) acc4[rt][nt] = (f4){0.f, 0.f, 0.f, 0.f};

  const size_t wbase = (size_t)m * 65536;
#pragma unroll 2
  for (int kt = 0; kt < 8; kt++) {
    h8 ah[4];
#pragma unroll
    for (int rt = 0; rt < 4; rt++) {
      const _Float16* p = u.h + (rt * 16 + lr) * HSS + kt * 32 + q * 8;
      h4 lo = *(const h4*)p;
      h4 hi = *(const h4*)(p + 4);
      ah[rt] = __builtin_shufflevector(lo, hi, 0, 1, 2, 3, 4, 5, 6, 7);
    }
#pragma unroll
    for (int nt = 0; nt < 2; nt++) {
      h8 bh = *(const h8*)(Wp + wbase + (((size_t)kt * 16 + (wv * 2 + nt)) * 64 + lane) * 8);
#pragma unroll
      for (int rt = 0; rt < 4; rt++)
        acc4[rt][nt] = __builtin_amdgcn_mfma_f32_16x16x32_f16(ah[rt], bh, acc4[rt][nt], 0, 0, 0);
    }
  }

  float bv[2];
#pragma unroll
  for (int nt = 0; nt < 2; nt++) bv[nt] = B2[m * 256 + wv * 32 + nt * 16 + lr];

  // ---- epilogue: two 32-row phases through LDS; 16 lanes per row ----
  float partLoss = 0.0f, partHit = 0.0f;
  for (int ph = 0; ph < 2; ph++) {
    __syncthreads();
#pragma unroll
    for (int rt2 = 0; rt2 < 2; rt2++) {
      int rt = ph * 2 + rt2;
#pragma unroll
      for (int nt = 0; nt < 2; nt++)
#pragma unroll
        for (int reg = 0; reg < 4; reg++) {
          int row = rt2 * 16 + q * 4 + reg;
          u.lg[row * LGS + wv * 32 + nt * 16 + lr] = acc4[rt][nt][reg] + bv[nt];
        }
    }
    __syncthreads();
    int rl = tid >> 4;                   // local row 0..31
    int n = n0 + ph * 32 + rl;
    int cl = tid & 15;                   // 16 lanes per row; lane cl owns cols cl*4 + 64k + e
    const float* lrow = u.lg + rl * LGS;
    f4 vv[4];
#pragma unroll
    for (int k = 0; k < 4; k++) vv[k] = *(const f4*)(lrow + cl * 4 + k * 64);
    if (pass == 0) {
      float mv = -1e30f; int mi = 0;
#pragma unroll
      for (int k = 0; k < 4; k++)
#pragma unroll
        for (int e = 0; e < 4; e++) {
          float v = vv[k][e];
          int c = cl * 4 + k * 64 + e;
          if (v > mv) { mv = v; mi = c; }
        }
#pragma unroll
      for (int off = 1; off < 16; off <<= 1) {
        float om = __shfl_xor(mv, off); int oi = __shfl_xor(mi, off);
        if (om > mv || (om == mv && oi < mi)) { mv = om; mi = oi; }
      }
      float s = 0.0f;
#pragma unroll
      for (int k = 0; k < 4; k++)
#pragma unroll
        for (int e = 0; e < 4; e++) s += __expf(vv[k][e] - mv);
#pragma unroll
      for (int off = 1; off < 16; off <<= 1) s += __shfl_xor(s, off);
      if (cl == 0) {
        float lse = mv + __logf(s);
        int t = (int)((targ[n] >> (m * 8)) & 0xFFull);
        partLoss += lse - lrow[t];
        partHit += (mi == t) ? 1.0f : 0.0f;
      }
    } else {
      float s = 0.0f;
#pragma unroll
      for (int k = 0; k < 4; k++)
#pragma unroll
        for (int e = 0; e < 4; e++) s += __expf(vv[k][e]);
#pragma unroll
      for (int off = 1; off < 16; off <<= 1) s += __shfl_xor(s, off);
      int np = nposA[n];
      const unsigned char* pl = poslist + (size_t)n * 64;
      float sp = 0.0f;
      for (int j2 = cl; j2 < np; j2 += 16) {
        int c = pl[j2];
        int t = (int)((cb64[c] >> (m * 8)) & 0xFFull);
        sp += lrow[t];
      }
#pragma unroll
      for (int off = 1; off < 16; off <<= 1) sp += __shfl_xor(sp, off);
      if (cl == 0) partLoss += __logf(s) - winv[n] * sp;
    }
  }
  // lanes 0,16,32,48 of each wave hold row results
  partLoss += __shfl_xor(partLoss, 16); partHit += __shfl_xor(partHit, 16);
  partLoss += __shfl_xor(partLoss, 32); partHit += __shfl_xor(partHit, 32);
  if (lane == 0) {
    if (pass == 0) {
      atomicAdd(&sl[0], partLoss);
      atomicAdd(&sl[2], partHit);
    } else {
      atomicAdd(&sl[1], partLoss);
    }
  }
  __syncthreads();
  if (tid == 0) {
    float* slot = accbuf + (blockIdx.x & 127) * 8;
    if (pass == 0) {
      atomicAdd(&slot[0], sl[0]);
      atomicAdd(&slot[2], sl[2]);
    } else {
      atomicAdd(&slot[1], sl[1]);
    }
  }
}

__global__ __launch_bounds__(128) void finalk(const float* __restrict__ accbuf, float* __restrict__ out) {
  int t = threadIdx.x;  // 0..127
  float v0 = accbuf[t * 8 + 0], v1 = accbuf[t * 8 + 1], v2 = accbuf[t * 8 + 2];
  float v3 = accbuf[t * 8 + 3], v4 = accbuf[t * 8 + 4];
#pragma unroll
  for (int off = 1; off < 64; off <<= 1) {
    v0 += __shfl_xor(v0, off); v1 += __shfl_xor(v1, off); v2 += __shfl_xor(v2, off);
    v3 += __shfl_xor(v3, off); v4 += __shfl_xor(v4, off);
  }
  __shared__ float s[2][5];
  if ((t & 63) == 0) {
    s[t >> 6][0] = v0; s[t >> 6][1] = v1; s[t >> 6][2] = v2; s[t >> 6][3] = v3; s[t >> 6][4] = v4;
  }
  __syncthreads();
  if (t == 0) {
    float a0 = s[0][0] + s[1][0], a1 = s[0][1] + s[1][1], a2 = s[0][2] + s[1][2];
    float a3 = s[0][3] + s[1][3], a4 = s[0][4] + s[1][4];
    float netLoss = a1 / (float)NR;
    float mapLoss = a0 / (float)NR;
    out[0] = netLoss + mapLoss;
    out[1] = netLoss;
    out[2] = mapLoss;
    out[3] = a2 / (float)(NR * MM);
    out[4] = a3 / a4;
  }
}

extern "C" void kernel_launch(void* const* d_in, const int* in_sizes, int n_in,
                              void* d_out, int out_size, void* d_ws, size_t ws_size,
                              hipStream_t stream) {
  const float* x = (const float*)d_in[0];
  const int* y = (const int*)d_in[1];
  const float* centroids = (const float*)d_in[2];
  const int* perm = (const int*)d_in[3];
  const void* tmap = d_in[4];
  const void* traw = d_in[5];
  const float* W1 = (const float*)d_in[6];
  const float* B1 = (const float*)d_in[7];
  const float* W2 = (const float*)d_in[8];
  const float* B2 = (const float*)d_in[9];
  float* out = (float*)d_out;

  char* w = (char*)d_ws;
  float* accbuf = (float*)w;                                  // 128 slots x 8 floats = 4 KB
  float* xp = (float*)(w + 4096);                             // 8 MB
  float* xm = xp + (size_t)NR * 64;                           // 8 MB
  ull* targ = (ull*)(xm + (size_t)NR * 64);                   // 256 KB
  ull* cb64 = targ + NR;                                      // 1 KB (128 slots)
  float* winv = (float*)(cb64 + 128);                         // 128 KB
  int* nposA = (int*)(winv + NR);                             // 128 KB
  unsigned char* poslist = (unsigned char*)(nposA + NR);      // 2 MB
  _Float16* Wp = (_Float16*)(poslist + (size_t)NR * 64);      // 1 MB (fp16 frags)
  _Float16* Wp1 = Wp + (1 << 19);                             // 128 KB (L1 frags)

  hipMemsetAsync(accbuf, 0, 4096, stream);

  // jax.random.key(1) -> (0,1); split -> kmap=(w0(0,2), w0(1,3)), kraw=(w1(0,2), w1(1,3))
  uint32_t a0, b0, a1, b1;
  tf2x32(0u, 1u, 0u, 2u, a0, b0);
  tf2x32(0u, 1u, 1u, 3u, a1, b1);

  packW2<<<256, 256, 0, stream>>>(W2, Wp);
  packW1<<<32, 256, 0, stream>>>(W1, Wp1);
  stage2<<<1, 128, 0, stream>>>(centroids, perm, cb64);
  stage1<<<NR / 4, 256, 0, stream>>>(x, y, perm, tmap, traw, a0, a1, b0, b1,
                                     xp, xm, targ, cb64, winv, poslist, nposA, accbuf);
  dim3 g(NR / 64, MM, 2);
  mapnet6<<<g, 512, 0, stream>>>(xm, xp, Wp1, B1, Wp, B2, targ, winv, poslist, nposA, cb64, accbuf);
  finalk<<<1, 128, 0, stream>>>(accbuf, out);
}

// Round 7
// 289.795 us; speedup vs baseline: 3.5649x; 1.0814x over previous
//
#include <hip/hip_runtime.h>
#include <stdint.h>

#define NR 32768
#define MM 8
#define NCLS 100
#define HALFN 1048576u
#define HSS 260   // fp16 stride for h plane rows: balanced banks for b64 frag reads
#define LGS 260   // float stride for logit rows

typedef _Float16 h8 __attribute__((ext_vector_type(8)));
typedef _Float16 h4 __attribute__((ext_vector_type(4)));
typedef float f4 __attribute__((ext_vector_type(4)));
typedef unsigned long long ull;

// ---------------- threefry2x32 (exact JAX semantics) ----------------
__host__ __device__ inline void tf2x32(uint32_t k0, uint32_t k1, uint32_t x0, uint32_t x1,
                                       uint32_t& o0, uint32_t& o1) {
  uint32_t ks0 = k0, ks1 = k1, ks2 = k0 ^ k1 ^ 0x1BD11BDAu;
  x0 += ks0; x1 += ks1;
#define TFR(r) { x0 += x1; x1 = (x1 << r) | (x1 >> (32 - r)); x1 ^= x0; }
  TFR(13) TFR(15) TFR(26) TFR(6)  x0 += ks1; x1 += ks2 + 1u;
  TFR(17) TFR(29) TFR(16) TFR(24) x0 += ks2; x1 += ks0 + 2u;
  TFR(13) TFR(15) TFR(26) TFR(6)  x0 += ks0; x1 += ks1 + 3u;
  TFR(17) TFR(29) TFR(16) TFR(24) x0 += ks1; x1 += ks2 + 4u;
  TFR(13) TFR(15) TFR(26) TFR(6)  x0 += ks2; x1 += ks0 + 5u;
#undef TFR
  o0 = x0; o1 = x1;
}

__device__ inline float tf_uniform(uint32_t k0, uint32_t k1, uint32_t i) {
  uint32_t o0, o1, b;
  if (i < HALFN) { tf2x32(k0, k1, i, i + HALFN, o0, o1); b = o0; }
  else           { tf2x32(k0, k1, i - HALFN, i, o0, o1); b = o1; }
  return __uint_as_float((b >> 9) | 0x3F800000u) - 1.0f;
}

// template dtype auto-detect: float32 {0,1.0f} / int32 {0,1} / bytes. 4 ones expected.
__device__ inline int load_tmpl(const void* p, int lane) {
  const unsigned* pi = (const unsigned*)p;
  unsigned w = pi[lane];
  ull okF = __ballot(w == 0u || w == 0x3F800000u);
  ull onF = __ballot(w == 0x3F800000u);
  ull okI = __ballot(w <= 1u);
  ull onI = __ballot(w == 1u);
  if (okF == ~0ull && __popcll(onF) == 4) return (w == 0x3F800000u) ? 1 : 0;
  if (okI == ~0ull && __popcll(onI) == 4) return (int)w;
  const unsigned char* pb = (const unsigned char*)p;
  return pb[lane] ? 1 : 0;
}

__device__ inline float rdlane(float v, int l) {
  return __int_as_float(__builtin_amdgcn_readlane(__float_as_int(v), l));
}

// ---------------- prep: packW2 + packW1 + stage2 fused ----------------
// blocks 0..255: W2 frags; 256..287: W1 frags; 288..312: centroid bits.
__global__ __launch_bounds__(256) void prep(const float* __restrict__ W2,
                                            const float* __restrict__ W1,
                                            const float* __restrict__ centroids,
                                            const int* __restrict__ perm,
                                            _Float16* __restrict__ Wp,
                                            _Float16* __restrict__ Wp1,
                                            ull* __restrict__ cb64) {
  int b = blockIdx.x, tid = threadIdx.x;
  if (b < 256) {
    // W2: gid = ((m*8+kt)*16+NT)*64 + q*16+lr ; elem j = W2[m][kt*32+q*8+j][NT*16+lr]
    int gid = b * 256 + tid;
    int lane6 = gid & 63, frag = gid >> 6;
    int NT = frag & 15, kt = (frag >> 4) & 7, m = frag >> 7;
    int q = lane6 >> 4, lr = lane6 & 15;
    const float* src = W2 + (size_t)m * 65536 + (size_t)(kt * 32 + q * 8) * 256 + NT * 16 + lr;
    h8 v;
#pragma unroll
    for (int j = 0; j < 8; j++) v[j] = (_Float16)src[j * 256];
    *(h8*)(Wp + (size_t)gid * 8) = v;
  } else if (b < 288) {
    // W1 frag (m, t): lane(q,lr) j -> A[hid=t*16+lr][k=q*8+j]: q0 = W1[j][hid], else 0
    int idx = (b - 256) * 256 + tid;  // 8192 total
    int lane = idx & 63, t = (idx >> 6) & 15, m = idx >> 10;
    int q = lane >> 4, lr = lane & 15;
    h8 v;
#pragma unroll
    for (int j = 0; j < 8; j++)
      v[j] = (q == 0) ? (_Float16)W1[(size_t)(m * 8 + j) * 256 + t * 16 + lr] : (_Float16)0.0f;
    *(h8*)(Wp1 + (size_t)idx * 8) = v;
  } else {
    // centroid bits: 4 classes per block, one wave each
    int c = (b - 288) * 4 + (tid >> 6);
    int lane = tid & 63;
    ull bits = __ballot(centroids[c * 64 + perm[lane]] > 0.0f);
    if (lane == 0) cb64[c] = bits;
  }
}

// ---------------- stage1: permute, flips, targets, y scan, hamming -----------
__global__ __launch_bounds__(256) void stage1(
    const float* __restrict__ x, const int* __restrict__ y, const int* __restrict__ perm,
    const void* tmap, const void* traw,
    uint32_t km0, uint32_t km1, uint32_t kr0, uint32_t kr1,
    float* __restrict__ xp, float* __restrict__ xm,
    ull* __restrict__ targ, const ull* __restrict__ cb64,
    float* __restrict__ winv, unsigned char* __restrict__ poslist, int* __restrict__ nposA,
    float* __restrict__ accbuf) {
  int wv = threadIdx.x >> 6, lane = threadIdx.x & 63;
  int n = blockIdx.x * 4 + wv;
  __shared__ float shh[2];
  if (threadIdx.x == 0) { shh[0] = 0.0f; shh[1] = 0.0f; }
  __syncthreads();

  int tm = load_tmpl(tmap, lane);
  int tr = load_tmpl(traw, lane);
  float xpv = x[n * 64 + perm[lane]];
  uint32_t i = (uint32_t)(n * 64 + lane);

  float um = tf_uniform(km0, km1, i);
  float ur = tf_uniform(kr0, kr1, i);
  int rank_m = 0, rank_r = 0;
#pragma unroll 16
  for (int k = 0; k < 64; k++) {
    float vm = rdlane(um, k);
    float vr = rdlane(ur, k);
    rank_m += (vm < um) || (vm == um && k < lane);
    rank_r += (vr < ur) || (vr == ur && k < lane);
  }
  ull fm = tm ? (1ull << rank_m) : 0ull;
  ull fr = tr ? (1ull << rank_r) : 0ull;
#pragma unroll
  for (int off = 1; off < 64; off <<= 1) {
    fm |= __shfl_xor(fm, off);
    fr |= __shfl_xor(fr, off);
  }

  float xmv = ((fm >> lane) & 1ull) ? -xpv : xpv;
  float rfv = ((fr >> lane) & 1ull) ? -xpv : xpv;
  xp[n * 64 + lane] = xpv;
  xm[n * 64 + lane] = xmv;
  ull t64 = __ballot(rfv > 0.0f);
  ull b64v = __ballot(xpv > 0.0f);

  int c1 = y[(size_t)n * NCLS + lane] > 0;
  int c2 = (lane < NCLS - 64) ? (y[(size_t)n * NCLS + 64 + lane] > 0) : 0;
  ull p0 = __ballot(c1);
  ull p1 = __ballot(c2);
  int cnt0 = __popcll(p0);
  float cnt = (float)(cnt0 + __popcll(p1));

  // parallel poslist scatter (ascending class order preserved)
  unsigned char* pl = poslist + (size_t)n * 64;
  ull below = (lane == 0) ? 0ull : (~0ull >> (64 - lane));
  if (c1) pl[__popcll(p0 & below)] = (unsigned char)lane;
  if (c2) pl[cnt0 + __popcll(p1 & below)] = (unsigned char)(64 + lane);

  // hamming contribution
  float px = (float)__popcll(b64v);
  float hsum = 0.0f;
  if (c1) { ull cb = cb64[lane]; hsum += px + (float)__popcll(cb) - 2.0f * (float)__popcll(b64v & cb); }
  if (c2) { ull cb = cb64[64 + lane]; hsum += px + (float)__popcll(cb) - 2.0f * (float)__popcll(b64v & cb); }
#pragma unroll
  for (int off = 1; off < 64; off <<= 1) hsum += __shfl_xor(hsum, off);

  if (lane == 0) {
    targ[n] = t64;
    winv[n] = 1.0f / cnt;
    nposA[n] = cnt0 + __popcll(p1);
    atomicAdd(&shh[0], hsum);
    atomicAdd(&shh[1], cnt);
  }
  __syncthreads();
  if (threadIdx.x == 0) {
    float* slot = accbuf + (blockIdx.x & 127) * 8;
    atomicAdd(&slot[3], shh[0]);
    atomicAdd(&slot[4], shh[1]);
  }
}

// ---------------- fused MLP (fp16 MFMA, 8-wave blocks) + loss epilogue ----
// grid (512, 8, 2); block 512 (8 waves). pass0 = map, pass1 = net.
__global__ __launch_bounds__(512, 6) void mapnet7(
    const float* __restrict__ Xm, const float* __restrict__ Xp,
    const _Float16* __restrict__ Wp1, const float* __restrict__ B1,
    const _Float16* __restrict__ Wp, const float* __restrict__ B2,
    const ull* __restrict__ targ, const float* __restrict__ winv,
    const unsigned char* __restrict__ poslist, const int* __restrict__ nposA,
    const ull* __restrict__ cb64, float* __restrict__ accbuf) {
  __shared__ union {
    _Float16 h[64 * HSS];      // fp16 h-plane, 33280 B
    float lg[32 * LGS];        // logit staging, 33280 B (exact alias)
  } u;
  __shared__ float sl[3];      // block loss accumulators
  const int tid = threadIdx.x, lane = tid & 63, wv = tid >> 6;
  const int q = lane >> 4, lr = lane & 15;
  const int m = blockIdx.y, pass = blockIdx.z;
  const int n0 = blockIdx.x * 64;
  const float* Xin = pass ? Xp : Xm;
  if (tid < 3) sl[tid] = 0.0f;

  // ---- L1 (transposed): wave wv covers rowblock rb = wv&3, t-range (wv>>2)*8..+7
  const int rb = wv & 3, tbase = (wv >> 2) * 8;
  h8 af;
  {
    const float* xsrc = Xin + (size_t)(n0 + rb * 16 + lr) * 64 + m * 8;
    f4 v0 = *(const f4*)xsrc;
    f4 v1 = *(const f4*)(xsrc + 4);
    float vf[8] = {v0.x, v0.y, v0.z, v0.w, v1.x, v1.y, v1.z, v1.w};
#pragma unroll
    for (int j = 0; j < 8; j++) af[j] = (q == 0) ? (_Float16)vf[j] : (_Float16)0.0f;
  }
#pragma unroll 4
  for (int tt = 0; tt < 8; tt++) {
    int t = tbase + tt;
    h8 wfrag = *(const h8*)(Wp1 + ((size_t)(m * 16 + t) * 64 + lane) * 8);
    f4 z = __builtin_amdgcn_mfma_f32_16x16x32_f16(wfrag, af, (f4){0.f, 0.f, 0.f, 0.f}, 0, 0, 0);
    f4 b1v = *(const f4*)(B1 + m * 256 + t * 16 + q * 4);
    h4 pk;
#pragma unroll
    for (int reg = 0; reg < 4; reg++) {
      float zz = z[reg] + b1v[reg];
      // silu via v_rcp_f32 (1 ulp; h is rounded to fp16 afterwards -> exact enough)
      pk[reg] = (_Float16)(zz * __builtin_amdgcn_rcpf(1.0f + __expf(-zz)));
    }
    *(h4*)(u.h + (size_t)(rb * 16 + lr) * HSS + t * 16 + q * 4) = pk;
  }
  __syncthreads();

  // ---- K loop: wave wv owns cols wv*32 + nt*16 + lr (nt 0..1), 64 rows ----
  f4 acc4[4][2];
#pragma unroll
  for (int rt = 0; rt < 4; rt++)
#pragma unroll
    for (int nt = 0; nt < 2; nt++) acc4[rt][nt] = (f4){0.f, 0.f, 0.f, 0.f};

  const size_t wbase = (size_t)m * 65536;
#pragma unroll 2
  for (int kt = 0; kt < 8; kt++) {
    h8 ah[4];
#pragma unroll
    for (int rt = 0; rt < 4; rt++) {
      const _Float16* p = u.h + (rt * 16 + lr) * HSS + kt * 32 + q * 8;
      h4 lo = *(const h4*)p;
      h4 hi = *(const h4*)(p + 4);
      ah[rt] = __builtin_shufflevector(lo, hi, 0, 1, 2, 3, 4, 5, 6, 7);
    }
#pragma unroll
    for (int nt = 0; nt < 2; nt++) {
      h8 bh = *(const h8*)(Wp + wbase + (((size_t)kt * 16 + (wv * 2 + nt)) * 64 + lane) * 8);
#pragma unroll
      for (int rt = 0; rt < 4; rt++)
        acc4[rt][nt] = __builtin_amdgcn_mfma_f32_16x16x32_f16(ah[rt], bh, acc4[rt][nt], 0, 0, 0);
    }
  }

  float bv[2];
#pragma unroll
  for (int nt = 0; nt < 2; nt++) bv[nt] = B2[m * 256 + wv * 32 + nt * 16 + lr];

  // ---- epilogue: two 32-row phases through LDS; 16 lanes per row ----
  float partLoss = 0.0f, partHit = 0.0f;
  for (int ph = 0; ph < 2; ph++) {
    __syncthreads();
#pragma unroll
    for (int rt2 = 0; rt2 < 2; rt2++) {
      int rt = ph * 2 + rt2;
#pragma unroll
      for (int nt = 0; nt < 2; nt++)
#pragma unroll
        for (int reg = 0; reg < 4; reg++) {
          int row = rt2 * 16 + q * 4 + reg;
          u.lg[row * LGS + wv * 32 + nt * 16 + lr] = acc4[rt][nt][reg] + bv[nt];
        }
    }
    __syncthreads();
    int rl = tid >> 4;                   // local row 0..31
    int n = n0 + ph * 32 + rl;
    int cl = tid & 15;                   // 16 lanes per row; lane cl owns cols cl*4 + 64k + e
    const float* lrow = u.lg + rl * LGS;
    f4 vv[4];
#pragma unroll
    for (int k = 0; k < 4; k++) vv[k] = *(const f4*)(lrow + cl * 4 + k * 64);
    if (pass == 0) {
      float mv = -1e30f; int mi = 0;
#pragma unroll
      for (int k = 0; k < 4; k++)
#pragma unroll
        for (int e = 0; e < 4; e++) {
          float v = vv[k][e];
          int c = cl * 4 + k * 64 + e;
          if (v > mv) { mv = v; mi = c; }
        }
#pragma unroll
      for (int off = 1; off < 16; off <<= 1) {
        float om = __shfl_xor(mv, off); int oi = __shfl_xor(mi, off);
        if (om > mv || (om == mv && oi < mi)) { mv = om; mi = oi; }
      }
      float s = 0.0f;
#pragma unroll
      for (int k = 0; k < 4; k++)
#pragma unroll
        for (int e = 0; e < 4; e++) s += __expf(vv[k][e] - mv);
#pragma unroll
      for (int off = 1; off < 16; off <<= 1) s += __shfl_xor(s, off);
      if (cl == 0) {
        float lse = mv + __logf(s);
        int t = (int)((targ[n] >> (m * 8)) & 0xFFull);
        partLoss += lse - lrow[t];
        partHit += (mi == t) ? 1.0f : 0.0f;
      }
    } else {
      float s = 0.0f;
#pragma unroll
      for (int k = 0; k < 4; k++)
#pragma unroll
        for (int e = 0; e < 4; e++) s += __expf(vv[k][e]);
#pragma unroll
      for (int off = 1; off < 16; off <<= 1) s += __shfl_xor(s, off);
      int np = nposA[n];
      const unsigned char* pl = poslist + (size_t)n * 64;
      float sp = 0.0f;
      for (int j2 = cl; j2 < np; j2 += 16) {
        int c = pl[j2];
        int t = (int)((cb64[c] >> (m * 8)) & 0xFFull);
        sp += lrow[t];
      }
#pragma unroll
      for (int off = 1; off < 16; off <<= 1) sp += __shfl_xor(sp, off);
      if (cl == 0) partLoss += __logf(s) - winv[n] * sp;
    }
  }
  // lanes 0,16,32,48 of each wave hold row results
  partLoss += __shfl_xor(partLoss, 16); partHit += __shfl_xor(partHit, 16);
  partLoss += __shfl_xor(partLoss, 32); partHit += __shfl_xor(partHit, 32);
  if (lane == 0) {
    if (pass == 0) {
      atomicAdd(&sl[0], partLoss);
      atomicAdd(&sl[2], partHit);
    } else {
      atomicAdd(&sl[1], partLoss);
    }
  }
  __syncthreads();
  if (tid == 0) {
    float* slot = accbuf + (blockIdx.x & 127) * 8;
    if (pass == 0) {
      atomicAdd(&slot[0], sl[0]);
      atomicAdd(&slot[2], sl[2]);
    } else {
      atomicAdd(&slot[1], sl[1]);
    }
  }
}

__global__ __launch_bounds__(128) void finalk(const float* __restrict__ accbuf, float* __restrict__ out) {
  int t = threadIdx.x;  // 0..127
  float v0 = accbuf[t * 8 + 0], v1 = accbuf[t * 8 + 1], v2 = accbuf[t * 8 + 2];
  float v3 = accbuf[t * 8 + 3], v4 = accbuf[t * 8 + 4];
#pragma unroll
  for (int off = 1; off < 64; off <<= 1) {
    v0 += __shfl_xor(v0, off); v1 += __shfl_xor(v1, off); v2 += __shfl_xor(v2, off);
    v3 += __shfl_xor(v3, off); v4 += __shfl_xor(v4, off);
  }
  __shared__ float s[2][5];
  if ((t & 63) == 0) {
    s[t >> 6][0] = v0; s[t >> 6][1] = v1; s[t >> 6][2] = v2; s[t >> 6][3] = v3; s[t >> 6][4] = v4;
  }
  __syncthreads();
  if (t == 0) {
    float a0 = s[0][0] + s[1][0], a1 = s[0][1] + s[1][1], a2 = s[0][2] + s[1][2];
    float a3 = s[0][3] + s[1][3], a4 = s[0][4] + s[1][4];
    float netLoss = a1 / (float)NR;
    float mapLoss = a0 / (float)NR;
    out[0] = netLoss + mapLoss;
    out[1] = netLoss;
    out[2] = mapLoss;
    out[3] = a2 / (float)(NR * MM);
    out[4] = a3 / a4;
  }
}

extern "C" void kernel_launch(void* const* d_in, const int* in_sizes, int n_in,
                              void* d_out, int out_size, void* d_ws, size_t ws_size,
                              hipStream_t stream) {
  const float* x = (const float*)d_in[0];
  const int* y = (const int*)d_in[1];
  const float* centroids = (const float*)d_in[2];
  const int* perm = (const int*)d_in[3];
  const void* tmap = d_in[4];
  const void* traw = d_in[5];
  const float* W1 = (const float*)d_in[6];
  const float* B1 = (const float*)d_in[7];
  const float* W2 = (const float*)d_in[8];
  const float* B2 = (const float*)d_in[9];
  float* out = (float*)d_out;

  char* w = (char*)d_ws;
  float* accbuf = (float*)w;                                  // 128 slots x 8 floats = 4 KB
  float* xp = (float*)(w + 4096);                             // 8 MB
  float* xm = xp + (size_t)NR * 64;                           // 8 MB
  ull* targ = (ull*)(xm + (size_t)NR * 64);                   // 256 KB
  ull* cb64 = targ + NR;                                      // 1 KB (128 slots)
  float* winv = (float*)(cb64 + 128);                         // 128 KB
  int* nposA = (int*)(winv + NR);                             // 128 KB
  unsigned char* poslist = (unsigned char*)(nposA + NR);      // 2 MB
  _Float16* Wp = (_Float16*)(poslist + (size_t)NR * 64);      // 1 MB (fp16 frags)
  _Float16* Wp1 = Wp + (1 << 19);                             // 128 KB (L1 frags)

  hipMemsetAsync(accbuf, 0, 4096, stream);

  // jax.random.key(1) -> (0,1); split -> kmap=(w0(0,2), w0(1,3)), kraw=(w1(0,2), w1(1,3))
  uint32_t a0, b0, a1, b1;
  tf2x32(0u, 1u, 0u, 2u, a0, b0);
  tf2x32(0u, 1u, 1u, 3u, a1, b1);

  prep<<<313, 256, 0, stream>>>(W2, W1, centroids, perm, Wp, Wp1, cb64);
  stage1<<<NR / 4, 256, 0, stream>>>(x, y, perm, tmap, traw, a0, a1, b0, b1,
                                     xp, xm, targ, cb64, winv, poslist, nposA, accbuf);
  dim3 g(NR / 64, MM, 2);
  mapnet7<<<g, 512, 0, stream>>>(xm, xp, Wp1, B1, Wp, B2, targ, winv, poslist, nposA, cb64, accbuf);
  finalk<<<1, 128, 0, stream>>>(accbuf, out);
}

// Round 8
// 276.829 us; speedup vs baseline: 3.7319x; 1.0468x over previous
//
#include <hip/hip_runtime.h>
#include <stdint.h>

#define NR 32768
#define MM 8
#define NCLS 100
#define HALFN 1048576u
#define HSS 260   // fp16 stride for h plane rows: balanced banks for b64 frag reads
#define LGS 260   // float stride for logit rows

typedef _Float16 h8 __attribute__((ext_vector_type(8)));
typedef _Float16 h4 __attribute__((ext_vector_type(4)));
typedef float f4 __attribute__((ext_vector_type(4)));
typedef unsigned long long ull;

// ---------------- threefry2x32 (exact JAX semantics) ----------------
__host__ __device__ inline void tf2x32(uint32_t k0, uint32_t k1, uint32_t x0, uint32_t x1,
                                       uint32_t& o0, uint32_t& o1) {
  uint32_t ks0 = k0, ks1 = k1, ks2 = k0 ^ k1 ^ 0x1BD11BDAu;
  x0 += ks0; x1 += ks1;
#define TFR(r) { x0 += x1; x1 = (x1 << r) | (x1 >> (32 - r)); x1 ^= x0; }
  TFR(13) TFR(15) TFR(26) TFR(6)  x0 += ks1; x1 += ks2 + 1u;
  TFR(17) TFR(29) TFR(16) TFR(24) x0 += ks2; x1 += ks0 + 2u;
  TFR(13) TFR(15) TFR(26) TFR(6)  x0 += ks0; x1 += ks1 + 3u;
  TFR(17) TFR(29) TFR(16) TFR(24) x0 += ks1; x1 += ks2 + 4u;
  TFR(13) TFR(15) TFR(26) TFR(6)  x0 += ks2; x1 += ks0 + 5u;
#undef TFR
  o0 = x0; o1 = x1;
}

__device__ inline float tf_uniform(uint32_t k0, uint32_t k1, uint32_t i) {
  uint32_t o0, o1, b;
  if (i < HALFN) { tf2x32(k0, k1, i, i + HALFN, o0, o1); b = o0; }
  else           { tf2x32(k0, k1, i - HALFN, i, o0, o1); b = o1; }
  return __uint_as_float((b >> 9) | 0x3F800000u) - 1.0f;
}

// template dtype auto-detect: float32 {0,1.0f} / int32 {0,1} / bytes. 4 ones expected.
__device__ inline int load_tmpl(const void* p, int lane) {
  const unsigned* pi = (const unsigned*)p;
  unsigned w = pi[lane];
  ull okF = __ballot(w == 0u || w == 0x3F800000u);
  ull onF = __ballot(w == 0x3F800000u);
  ull okI = __ballot(w <= 1u);
  ull onI = __ballot(w == 1u);
  if (okF == ~0ull && __popcll(onF) == 4) return (w == 0x3F800000u) ? 1 : 0;
  if (okI == ~0ull && __popcll(onI) == 4) return (int)w;
  const unsigned char* pb = (const unsigned char*)p;
  return pb[lane] ? 1 : 0;
}

__device__ inline float rdlane(float v, int l) {
  return __int_as_float(__builtin_amdgcn_readlane(__float_as_int(v), l));
}

__device__ inline uint32_t packh2(float a, float b) {
  union { _Float16 h[2]; uint32_t u; } cv;
  cv.h[0] = (_Float16)a; cv.h[1] = (_Float16)b;
  return cv.u;
}

// ---------------- stage1p: stage1 (no hamming) + prep fused ----------------
// blocks 0..8191: per-row permute/flip/targets/y-scan (4 rows/block).
// blocks 8192..8447: W2 frag pack; 8448..8479: W1 frag pack; 8480..8504: cb64.
__global__ __launch_bounds__(256) void stage1p(
    const float* __restrict__ x, const int* __restrict__ y, const int* __restrict__ perm,
    const void* tmap, const void* traw,
    uint32_t km0, uint32_t km1, uint32_t kr0, uint32_t kr1,
    const float* __restrict__ W2, const float* __restrict__ W1,
    const float* __restrict__ centroids,
    _Float16* __restrict__ Wp, _Float16* __restrict__ Wp1, ull* __restrict__ cb64,
    uint32_t* __restrict__ xp16, uint32_t* __restrict__ xm16,
    ull* __restrict__ targ, ull* __restrict__ xb,
    float* __restrict__ winv, unsigned char* __restrict__ poslist, int* __restrict__ nposA) {
  int b = blockIdx.x, tid = threadIdx.x;
  if (b >= NR / 4) {
    int pb = b - NR / 4;
    if (pb < 256) {
      // W2: gid = ((m*8+kt)*16+NT)*64 + q*16+lr ; elem j = W2[m][kt*32+q*8+j][NT*16+lr]
      int gid = pb * 256 + tid;
      int lane6 = gid & 63, frag = gid >> 6;
      int NT = frag & 15, kt = (frag >> 4) & 7, m = frag >> 7;
      int q = lane6 >> 4, lr = lane6 & 15;
      const float* src = W2 + (size_t)m * 65536 + (size_t)(kt * 32 + q * 8) * 256 + NT * 16 + lr;
      h8 v;
#pragma unroll
      for (int j = 0; j < 8; j++) v[j] = (_Float16)src[j * 256];
      *(h8*)(Wp + (size_t)gid * 8) = v;
    } else if (pb < 288) {
      // W1 frag (m, t): lane(q,lr) j -> A[hid=t*16+lr][k=q*8+j]: q0 = W1[j][hid], else 0
      int idx = (pb - 256) * 256 + tid;  // 8192 total
      int lane = idx & 63, t = (idx >> 6) & 15, m = idx >> 10;
      int q = lane >> 4, lr = lane & 15;
      h8 v;
#pragma unroll
      for (int j = 0; j < 8; j++)
        v[j] = (q == 0) ? (_Float16)W1[(size_t)(m * 8 + j) * 256 + t * 16 + lr] : (_Float16)0.0f;
      *(h8*)(Wp1 + (size_t)idx * 8) = v;
    } else {
      // centroid bits: 4 classes per block, one wave each (25 blocks x 4 = 100)
      int c = (pb - 288) * 4 + (tid >> 6);
      int lane = tid & 63;
      ull bits = __ballot(centroids[c * 64 + perm[lane]] > 0.0f);
      if (lane == 0) cb64[c] = bits;
    }
    return;
  }

  int wv = tid >> 6, lane = tid & 63;
  int n = b * 4 + wv;

  int tm = load_tmpl(tmap, lane);
  int tr = load_tmpl(traw, lane);
  float xpv = x[n * 64 + perm[lane]];
  uint32_t i = (uint32_t)(n * 64 + lane);

  float um = tf_uniform(km0, km1, i);
  float ur = tf_uniform(kr0, kr1, i);
  int rank_m = 0, rank_r = 0;
#pragma unroll 16
  for (int k = 0; k < 64; k++) {
    float vm = rdlane(um, k);
    float vr = rdlane(ur, k);
    rank_m += (vm < um) || (vm == um && k < lane);
    rank_r += (vr < ur) || (vr == ur && k < lane);
  }
  ull fm = tm ? (1ull << rank_m) : 0ull;
  ull fr = tr ? (1ull << rank_r) : 0ull;
#pragma unroll
  for (int off = 1; off < 64; off <<= 1) {
    fm |= __shfl_xor(fm, off);
    fr |= __shfl_xor(fr, off);
  }

  float xmv = ((fm >> lane) & 1ull) ? -xpv : xpv;
  float rfv = ((fr >> lane) & 1ull) ? -xpv : xpv;
  // fp16 outputs (identical rounding to mapnet's former in-kernel cvt)
  float xp_o = __shfl_xor(xpv, 1);
  float xm_o = __shfl_xor(xmv, 1);
  if ((lane & 1) == 0) {
    xp16[n * 32 + (lane >> 1)] = packh2(xpv, xp_o);
    xm16[n * 32 + (lane >> 1)] = packh2(xmv, xm_o);
  }
  ull t64 = __ballot(rfv > 0.0f);
  ull b64v = __ballot(xpv > 0.0f);

  int c1 = y[(size_t)n * NCLS + lane] > 0;
  int c2 = (lane < NCLS - 64) ? (y[(size_t)n * NCLS + 64 + lane] > 0) : 0;
  ull p0 = __ballot(c1);
  ull p1 = __ballot(c2);
  int cnt0 = __popcll(p0);
  float cnt = (float)(cnt0 + __popcll(p1));

  // parallel poslist scatter (ascending class order preserved)
  unsigned char* pl = poslist + (size_t)n * 64;
  ull below = (lane == 0) ? 0ull : (~0ull >> (64 - lane));
  if (c1) pl[__popcll(p0 & below)] = (unsigned char)lane;
  if (c2) pl[cnt0 + __popcll(p1 & below)] = (unsigned char)(64 + lane);

  if (lane == 0) {
    targ[n] = t64;
    xb[n] = b64v;
    winv[n] = 1.0f / cnt;
    nposA[n] = cnt0 + __popcll(p1);
  }
}

// ---------------- fused MLP + loss epilogue + hamming slice ----
// grid (512, 8, 3); block 512 (8 waves). z0 = map, z1 = net, z2 = hamming.
__global__ __launch_bounds__(512, 6) void mapnet8(
    const uint32_t* __restrict__ Xm16, const uint32_t* __restrict__ Xp16,
    const _Float16* __restrict__ Wp1, const float* __restrict__ B1,
    const _Float16* __restrict__ Wp, const float* __restrict__ B2,
    const ull* __restrict__ targ, const float* __restrict__ winv,
    const unsigned char* __restrict__ poslist, const int* __restrict__ nposA,
    const ull* __restrict__ cb64, const ull* __restrict__ xb,
    float* __restrict__ accbuf) {
  __shared__ union {
    _Float16 h[64 * HSS];      // fp16 h-plane, 33280 B
    float lg[32 * LGS];        // logit staging, 33280 B (exact alias)
  } u;
  __shared__ float sl[3];      // block accumulators
  const int tid = threadIdx.x, lane = tid & 63, wv = tid >> 6;
  const int q = lane >> 4, lr = lane & 15;
  const int m = blockIdx.y, pass = blockIdx.z;
  const int n0 = blockIdx.x * 64;
  if (tid < 3) sl[tid] = 0.0f;

  if (pass == 2) {
    // hamming + cnt: 8 rows per block (one per wave)
    __syncthreads();
    int flat = blockIdx.y * 512 + blockIdx.x;   // 0..4095
    int n = flat * 8 + wv;
    ull xv = xb[n];
    float px = (float)__popcll(xv);
    int np = nposA[n];
    float hs = 0.0f;
    if (lane < np) {
      int c = poslist[(size_t)n * 64 + lane];
      ull cb = cb64[c];
      hs = px + (float)__popcll(cb) - 2.0f * (float)__popcll(xv & cb);
    }
#pragma unroll
    for (int off = 1; off < 64; off <<= 1) hs += __shfl_xor(hs, off);
    if (lane == 0) {
      atomicAdd(&sl[0], hs);
      atomicAdd(&sl[1], (float)np);
    }
    __syncthreads();
    if (tid == 0) {
      float* slot = accbuf + (flat & 127) * 8;
      atomicAdd(&slot[3], sl[0]);
      atomicAdd(&slot[4], sl[1]);
    }
    return;
  }

  const uint32_t* Xin = pass ? Xp16 : Xm16;

  // ---- L1 (transposed): wave wv covers rowblock rb = wv&3, t-range (wv>>2)*8..+7
  const int rb = wv & 3, tbase = (wv >> 2) * 8;
  h8 af;
  {
    const _Float16* xsrc = (const _Float16*)(Xin + (size_t)(n0 + rb * 16 + lr) * 32) + m * 8;
    h8 xv = *(const h8*)xsrc;
    h8 zero = {(_Float16)0.0f, (_Float16)0.0f, (_Float16)0.0f, (_Float16)0.0f,
               (_Float16)0.0f, (_Float16)0.0f, (_Float16)0.0f, (_Float16)0.0f};
    af = (q == 0) ? xv : zero;
  }
#pragma unroll 4
  for (int tt = 0; tt < 8; tt++) {
    int t = tbase + tt;
    h8 wfrag = *(const h8*)(Wp1 + ((size_t)(m * 16 + t) * 64 + lane) * 8);
    f4 z = __builtin_amdgcn_mfma_f32_16x16x32_f16(wfrag, af, (f4){0.f, 0.f, 0.f, 0.f}, 0, 0, 0);
    f4 b1v = *(const f4*)(B1 + m * 256 + t * 16 + q * 4);
    h4 pk;
#pragma unroll
    for (int reg = 0; reg < 4; reg++) {
      float zz = z[reg] + b1v[reg];
      // silu via v_rcp_f32 (1 ulp; h is rounded to fp16 afterwards -> exact enough)
      pk[reg] = (_Float16)(zz * __builtin_amdgcn_rcpf(1.0f + __expf(-zz)));
    }
    *(h4*)(u.h + (size_t)(rb * 16 + lr) * HSS + t * 16 + q * 4) = pk;
  }
  __syncthreads();

  // ---- K loop: wave wv owns cols wv*32 + nt*16 + lr (nt 0..1), 64 rows ----
  f4 acc4[4][2];
#pragma unroll
  for (int rt = 0; rt < 4; rt++)
#pragma unroll
    for (int nt = 0; nt < 2; nt++) acc4[rt][nt] = (f4){0.f, 0.f, 0.f, 0.f};

  const size_t wbase = (size_t)m * 65536;
#pragma unroll 2
  for (int kt = 0; kt < 8; kt++) {
    h8 ah[4];
#pragma unroll
    for (int rt = 0; rt < 4; rt++) {
      const _Float16* p = u.h + (rt * 16 + lr) * HSS + kt * 32 + q * 8;
      h4 lo = *(const h4*)p;
      h4 hi = *(const h4*)(p + 4);
      ah[rt] = __builtin_shufflevector(lo, hi, 0, 1, 2, 3, 4, 5, 6, 7);
    }
#pragma unroll
    for (int nt = 0; nt < 2; nt++) {
      h8 bh = *(const h8*)(Wp + wbase + (((size_t)kt * 16 + (wv * 2 + nt)) * 64 + lane) * 8);
#pragma unroll
      for (int rt = 0; rt < 4; rt++)
        acc4[rt][nt] = __builtin_amdgcn_mfma_f32_16x16x32_f16(ah[rt], bh, acc4[rt][nt], 0, 0, 0);
    }
  }

  float bv[2];
#pragma unroll
  for (int nt = 0; nt < 2; nt++) bv[nt] = B2[m * 256 + wv * 32 + nt * 16 + lr];

  // ---- epilogue: two 32-row phases through LDS; 16 lanes per row ----
  float partLoss = 0.0f, partHit = 0.0f;
  for (int ph = 0; ph < 2; ph++) {
    __syncthreads();
#pragma unroll
    for (int rt2 = 0; rt2 < 2; rt2++) {
      int rt = ph * 2 + rt2;
#pragma unroll
      for (int nt = 0; nt < 2; nt++)
#pragma unroll
        for (int reg = 0; reg < 4; reg++) {
          int row = rt2 * 16 + q * 4 + reg;
          u.lg[row * LGS + wv * 32 + nt * 16 + lr] = acc4[rt][nt][reg] + bv[nt];
        }
    }
    __syncthreads();
    int rl = tid >> 4;                   // local row 0..31
    int n = n0 + ph * 32 + rl;
    int cl = tid & 15;                   // 16 lanes per row; lane cl owns cols cl*4 + 64k + e
    const float* lrow = u.lg + rl * LGS;
    f4 vv[4];
#pragma unroll
    for (int k = 0; k < 4; k++) vv[k] = *(const f4*)(lrow + cl * 4 + k * 64);
    if (pass == 0) {
      float mv = -1e30f; int mi = 0;
#pragma unroll
      for (int k = 0; k < 4; k++)
#pragma unroll
        for (int e = 0; e < 4; e++) {
          float v = vv[k][e];
          int c = cl * 4 + k * 64 + e;
          if (v > mv) { mv = v; mi = c; }
        }
#pragma unroll
      for (int off = 1; off < 16; off <<= 1) {
        float om = __shfl_xor(mv, off); int oi = __shfl_xor(mi, off);
        if (om > mv || (om == mv && oi < mi)) { mv = om; mi = oi; }
      }
      float s = 0.0f;
#pragma unroll
      for (int k = 0; k < 4; k++)
#pragma unroll
        for (int e = 0; e < 4; e++) s += __expf(vv[k][e] - mv);
#pragma unroll
      for (int off = 1; off < 16; off <<= 1) s += __shfl_xor(s, off);
      if (cl == 0) {
        float lse = mv + __logf(s);
        int t = (int)((targ[n] >> (m * 8)) & 0xFFull);
        partLoss += lse - lrow[t];
        partHit += (mi == t) ? 1.0f : 0.0f;
      }
    } else {
      float s = 0.0f;
#pragma unroll
      for (int k = 0; k < 4; k++)
#pragma unroll
        for (int e = 0; e < 4; e++) s += __expf(vv[k][e]);
#pragma unroll
      for (int off = 1; off < 16; off <<= 1) s += __shfl_xor(s, off);
      int np = nposA[n];
      const unsigned char* pl = poslist + (size_t)n * 64;
      float sp = 0.0f;
      for (int j2 = cl; j2 < np; j2 += 16) {
        int c = pl[j2];
        int t = (int)((cb64[c] >> (m * 8)) & 0xFFull);
        sp += lrow[t];
      }
#pragma unroll
      for (int off = 1; off < 16; off <<= 1) sp += __shfl_xor(sp, off);
      if (cl == 0) partLoss += __logf(s) - winv[n] * sp;
    }
  }
  // lanes 0,16,32,48 of each wave hold row results
  partLoss += __shfl_xor(partLoss, 16); partHit += __shfl_xor(partHit, 16);
  partLoss += __shfl_xor(partLoss, 32); partHit += __shfl_xor(partHit, 32);
  if (lane == 0) {
    if (pass == 0) {
      atomicAdd(&sl[0], partLoss);
      atomicAdd(&sl[2], partHit);
    } else {
      atomicAdd(&sl[1], partLoss);
    }
  }
  __syncthreads();
  if (tid == 0) {
    float* slot = accbuf + (blockIdx.x & 127) * 8;
    if (pass == 0) {
      atomicAdd(&slot[0], sl[0]);
      atomicAdd(&slot[2], sl[2]);
    } else {
      atomicAdd(&slot[1], sl[1]);
    }
  }
}

__global__ __launch_bounds__(128) void finalk(const float* __restrict__ accbuf, float* __restrict__ out) {
  int t = threadIdx.x;  // 0..127
  float v0 = accbuf[t * 8 + 0], v1 = accbuf[t * 8 + 1], v2 = accbuf[t * 8 + 2];
  float v3 = accbuf[t * 8 + 3], v4 = accbuf[t * 8 + 4];
#pragma unroll
  for (int off = 1; off < 64; off <<= 1) {
    v0 += __shfl_xor(v0, off); v1 += __shfl_xor(v1, off); v2 += __shfl_xor(v2, off);
    v3 += __shfl_xor(v3, off); v4 += __shfl_xor(v4, off);
  }
  __shared__ float s[2][5];
  if ((t & 63) == 0) {
    s[t >> 6][0] = v0; s[t >> 6][1] = v1; s[t >> 6][2] = v2; s[t >> 6][3] = v3; s[t >> 6][4] = v4;
  }
  __syncthreads();
  if (t == 0) {
    float a0 = s[0][0] + s[1][0], a1 = s[0][1] + s[1][1], a2 = s[0][2] + s[1][2];
    float a3 = s[0][3] + s[1][3], a4 = s[0][4] + s[1][4];
    float netLoss = a1 / (float)NR;
    float mapLoss = a0 / (float)NR;
    out[0] = netLoss + mapLoss;
    out[1] = netLoss;
    out[2] = mapLoss;
    out[3] = a2 / (float)(NR * MM);
    out[4] = a3 / a4;
  }
}

extern "C" void kernel_launch(void* const* d_in, const int* in_sizes, int n_in,
                              void* d_out, int out_size, void* d_ws, size_t ws_size,
                              hipStream_t stream) {
  const float* x = (const float*)d_in[0];
  const int* y = (const int*)d_in[1];
  const float* centroids = (const float*)d_in[2];
  const int* perm = (const int*)d_in[3];
  const void* tmap = d_in[4];
  const void* traw = d_in[5];
  const float* W1 = (const float*)d_in[6];
  const float* B1 = (const float*)d_in[7];
  const float* W2 = (const float*)d_in[8];
  const float* B2 = (const float*)d_in[9];
  float* out = (float*)d_out;

  char* w = (char*)d_ws;
  float* accbuf = (float*)w;                                  // 128 slots x 8 floats = 4 KB
  uint32_t* xp16 = (uint32_t*)(w + 4096);                     // 4 MB (fp16 pairs)
  uint32_t* xm16 = xp16 + (size_t)NR * 32;                    // 4 MB
  ull* targ = (ull*)(xm16 + (size_t)NR * 32);                 // 256 KB
  ull* cb64 = targ + NR;                                      // 1 KB (128 slots)
  ull* xb = cb64 + 128;                                       // 256 KB
  float* winv = (float*)(xb + NR);                            // 128 KB
  int* nposA = (int*)(winv + NR);                             // 128 KB
  unsigned char* poslist = (unsigned char*)(nposA + NR);      // 2 MB
  _Float16* Wp = (_Float16*)(poslist + (size_t)NR * 64);      // 1 MB (fp16 frags)
  _Float16* Wp1 = Wp + (1 << 19);                             // 128 KB (L1 frags)

  hipMemsetAsync(accbuf, 0, 4096, stream);

  // jax.random.key(1) -> (0,1); split -> kmap=(w0(0,2), w0(1,3)), kraw=(w1(0,2), w1(1,3))
  uint32_t a0, b0, a1, b1;
  tf2x32(0u, 1u, 0u, 2u, a0, b0);
  tf2x32(0u, 1u, 1u, 3u, a1, b1);

  stage1p<<<NR / 4 + 313, 256, 0, stream>>>(x, y, perm, tmap, traw, a0, a1, b0, b1,
                                            W2, W1, centroids, Wp, Wp1, cb64,
                                            xp16, xm16, targ, xb, winv, poslist, nposA);
  dim3 g(NR / 64, MM, 3);
  mapnet8<<<g, 512, 0, stream>>>(xm16, xp16, Wp1, B1, Wp, B2, targ, winv, poslist, nposA,
                                 cb64, xb, accbuf);
  finalk<<<1, 128, 0, stream>>>(accbuf, out);
}